// Round 15
// baseline (1521.837 us; speedup 1.0000x reference)
//
#include <hip/hip_runtime.h>
#include <stdint.h>
#include <math.h>

// ---------------- problem constants ----------------
#define B_    16
#define C_    3
#define HIMG  128
#define E_    512
#define NH_   8
#define S_    257
#define T_    256
#define MTOK  4096         // B*T
#define MSEQ  4112         // B*S
#define HID_  2048
#define SP_   288          // S padded to mult of 32
#define SLAB  (288*288)
#define PS    2105344L     // partial-slab stride (MSEQ*512 elements)
#define INV_SQRT_E 0.044194173824159216f

typedef __attribute__((ext_vector_type(8))) __bf16 bf16x8;
typedef __attribute__((ext_vector_type(4))) float f32x4;

// ---------------- global->LDS direct (16B/lane) ----------------
__device__ __forceinline__ void gload16(const void* g, const void* lds)
{
    __builtin_amdgcn_global_load_lds(
        (const __attribute__((address_space(1))) uint32_t*)(uintptr_t)g,
        (__attribute__((address_space(3))) uint32_t*)(uint32_t)(uintptr_t)lds,
        16, 0, 0);
}

// ---------------- bf16 MFMA GEMM core (4-deep ring pipeline) ----------------
// C[M,N] = scale * (A[M,K] . Bt[N,K]^T) (+bias[n]) (leaky opt)
// A, Bt bf16 row-major. BM=WMW*64, BN=WNW*32. Wave tile 64x32 (4x2 frags).
// LDS: [row][chunk^((row>>1)&3)] 16B chunks, pre-swizzled global source.
// Pipeline: 4 LDS slots, prefetch depth 3, counted vmcnt + raw s_barrier;
// s_setprio(1) around the MFMA cluster (T5 — phase-split schedule).
// VSPLIT: cols n>=512 are V-projection -> written transposed into vTout[bh][p][t].
// Staged rows beyond M must be readable (callers pad allocations); K % 32 == 0.
template<int WMW, int WNW, bool LEAKY, bool OUTF32, bool VSPLIT>
__device__ __forceinline__ void gemm_core(
    const __bf16* __restrict__ A, int lda,
    const __bf16* __restrict__ Bt, int ldb,
    void* __restrict__ C, int ldc,
    const float* __restrict__ bias, float scale,
    int M, int N, int K, int tm, int tn, __bf16* __restrict__ vTout)
{
    constexpr int BM  = WMW * 64;
    constexpr int BN  = WNW * 32;
    constexpr int T   = WMW * WNW * 64;
    constexpr int ACH = BM * 4;              // 16B chunks per A tile
    constexpr int BCH = BN * 4;
    constexpr int LPT = ACH / T + BCH / T;   // vmem instrs per thread per stage
    __shared__ __align__(16) __bf16 sA[4][BM * 32];
    __shared__ __align__(16) __bf16 sB[4][BN * 32];

    const int tid  = threadIdx.x;
    const int lane = tid & 63;
    const int wid  = tid >> 6;
    const int wm   = wid / WNW;
    const int wn   = wid % WNW;
    const int lh   = lane >> 4;
    const int ll   = lane & 15;

    const __bf16* Ab = A + (long)tm * BM * lda;
    const __bf16* Bb = Bt + (long)tn * BN * ldb;

    f32x4 acc[4][2] = {};
    const int nst = K >> 5;

    auto stage = [&](int buf, int k0) {
#pragma unroll
        for (int rr = 0; rr < ACH / T; ++rr) {
            const int L = rr * T + tid;
            const int row = L >> 2;
            const int gch = (L & 3) ^ ((row >> 1) & 3);
            gload16(Ab + (long)row * lda + k0 + gch * 8,
                    (const char*)(&sA[buf][0]) + (rr * T + (wid << 6)) * 16);
        }
#pragma unroll
        for (int rr = 0; rr < BCH / T; ++rr) {
            const int L = rr * T + tid;
            const int row = L >> 2;
            const int gch = (L & 3) ^ ((row >> 1) & 3);
            gload16(Bb + (long)row * ldb + k0 + gch * 8,
                    (const char*)(&sB[buf][0]) + (rr * T + (wid << 6)) * 16);
        }
    };

    const int PF = nst < 3 ? nst : 3;
    for (int s = 0; s < PF; ++s) stage(s & 3, s << 5);

    for (int st = 0; st < nst; ++st) {
        const int rem = nst - 1 - st;
        if (rem >= 2)      asm volatile("s_waitcnt vmcnt(%0)" :: "n"(2 * LPT) : "memory");
        else if (rem == 1) asm volatile("s_waitcnt vmcnt(%0)" :: "n"(LPT) : "memory");
        else               asm volatile("s_waitcnt vmcnt(0)" ::: "memory");
        __builtin_amdgcn_s_barrier();
        __builtin_amdgcn_sched_barrier(0);

        if (st + 3 < nst) stage((st + 3) & 3, (st + 3) << 5);

        const int cur = st & 3;
        bf16x8 afr[4], bfr[2];
#pragma unroll
        for (int i = 0; i < 4; ++i) {
            const int rw = wm * 64 + i * 16 + ll;
            const int c  = lh ^ ((rw >> 1) & 3);
            afr[i] = *reinterpret_cast<const bf16x8*>(&sA[cur][rw * 32 + c * 8]);
        }
#pragma unroll
        for (int j = 0; j < 2; ++j) {
            const int rw = wn * 32 + j * 16 + ll;
            const int c  = lh ^ ((rw >> 1) & 3);
            bfr[j] = *reinterpret_cast<const bf16x8*>(&sB[cur][rw * 32 + c * 8]);
        }
        __builtin_amdgcn_s_setprio(1);
#pragma unroll
        for (int i = 0; i < 4; ++i)
#pragma unroll
            for (int j = 0; j < 2; ++j)
                acc[i][j] = __builtin_amdgcn_mfma_f32_16x16x32_bf16(
                                afr[i], bfr[j], acc[i][j], 0, 0, 0);
        __builtin_amdgcn_s_setprio(0);
    }

    // epilogue: D frag col=lane&15, row=(lane>>4)*4+reg  [m89-verified]
#pragma unroll
    for (int i = 0; i < 4; ++i)
#pragma unroll
        for (int ii = 0; ii < 4; ++ii) {
            const int m = tm * BM + wm * 64 + i * 16 + lh * 4 + ii;
            if (m >= M) continue;
#pragma unroll
            for (int j = 0; j < 2; ++j) {
                const int n = tn * BN + wn * 32 + j * 16 + ll;
                if (n >= N) continue;
                float v = acc[i][j][ii] * scale;
                if (bias) v += bias[n];
                if (LEAKY) v = v > 0.f ? v : 0.2f * v;
                if (VSPLIT && n >= 512) {
                    const int b = m / S_;
                    const int t = m - b * S_;
                    const int hp = n - 512;
                    vTout[(((long)(b * 8 + (hp >> 6)) * 64) + (hp & 63)) * SP_ + t] =
                        (__bf16)v;
                } else if (OUTF32) {
                    ((float*)C)[(long)m * ldc + n] = v;
                } else {
                    ((__bf16*)C)[(long)m * ldc + n] = (__bf16)v;
                }
            }
        }
}

__device__ __forceinline__ int xcd_swizzle(int wg, int nwg)
{
    const int q = nwg >> 3, r = nwg & 7;
    if (q == 0) return wg;
    const int xcd = wg & 7, off = wg >> 3;
    return (xcd < r ? xcd * (q + 1) : r * (q + 1) + (xcd - r) * q) + off;
}

// flat-grid GEMM, bijective XCD swizzle, tn fastest (A panels L2-resident)
template<int WMW, int WNW, bool LEAKY, bool OUTF32, bool VSPLIT>
__global__ __launch_bounds__(WMW * WNW * 64) void gemm_k(
    const __bf16* __restrict__ A, int lda, const __bf16* __restrict__ Bt, int ldb,
    void* __restrict__ C, int ldc, const float* __restrict__ bias, float scale,
    int M, int N, int K, int ntn, __bf16* __restrict__ vTout)
{
    const int wg = xcd_swizzle(blockIdx.x, gridDim.x);
    gemm_core<WMW, WNW, LEAKY, OUTF32, VSPLIT>(A, lda, Bt, ldb, C, ldc, bias, scale,
                                               M, N, K, wg / ntn, wg % ntn, vTout);
}

// split-K GEMM: blockIdx.y = K-part; bf16 partial slabs; consumer sums.
template<int WMW, int WNW>
__global__ __launch_bounds__(WMW * WNW * 64) void gemm_split_k(
    const __bf16* __restrict__ A, int lda, const __bf16* __restrict__ Bt, int ldb,
    __bf16* __restrict__ P, long pstride, const float* __restrict__ bias,
    int M, int N, int K, int npart, int ntn)
{
    const int part = blockIdx.y;
    const int Kp = K / npart;
    const int wg = xcd_swizzle(blockIdx.x, gridDim.x);
    gemm_core<WMW, WNW, false, false, false>(A + (long)part * Kp, lda,
                                             Bt + (long)part * Kp, ldb,
                                             P + (long)part * pstride, N,
                                             part == 0 ? bias : nullptr, 1.f,
                                             M, N, Kp, wg / ntn, wg % ntn, nullptr);
}

// qv: qv[b,s,(h,p)] = sum_t qh[h,s,t] * v[b,t,(h,p)]  (4-wave core)
__global__ __launch_bounds__(256) void qv_k(const __bf16* __restrict__ qhb,
                                            const __bf16* __restrict__ vT,
                                            __bf16* __restrict__ qvcat)
{
    const int bh = blockIdx.z, b = bh >> 3, h = bh & 7;
    gemm_core<2, 2, false, false, false>(qhb + (long)h * SLAB, SP_,
                                         vT + (long)bh * 64 * SP_, SP_,
                                         qvcat + (long)b * S_ * E_ + h * 64, E_,
                                         nullptr, 1.f, S_, 64, SP_, blockIdx.x, 0,
                                         nullptr);
}

// ---------------- fused attention: scores -> online softmax -> PV -----------
// grid (5 i-tiles, 128 bh), 256 threads (4 waves, 16 i-rows each).
// QV/V double-buffered: prefetch jt+1 during compute; one barrier per tile.
__global__ __launch_bounds__(256) void fa_k(const __bf16* __restrict__ kcat,
                                            const __bf16* __restrict__ qvcat,
                                            const __bf16* __restrict__ vT,
                                            __bf16* __restrict__ ocat)
{
    __shared__ __align__(16) __bf16 sK[64 * 64], sQV[2][64 * 64], sV[2][64 * 64];
    __shared__ __align__(16) __bf16 sP[4][16 * 64];
    const int bh = blockIdx.y, b = bh >> 3, h = bh & 7;
    const int i0 = blockIdx.x * 64;
    const int tid = threadIdx.x, lane = tid & 63, wid = tid >> 6;
    const int ll = lane & 15, lh = lane >> 4;

    const __bf16* kSrc = kcat + ((long)(b * S_ + i0)) * 512 + h * 64;
    const __bf16* qvB  = qvcat + (long)b * S_ * E_ + h * 64;
    const __bf16* vTb  = vT + (long)bh * 64 * SP_;

    auto stage64 = [&](__bf16* lds, const __bf16* src, int ldsrc) {
#pragma unroll
        for (int r = 0; r < 2; ++r) {
            const int L = r * 256 + wid * 64 + lane;
            const int row = L >> 3, c = L & 7;
            const int sc = c ^ (row & 7);
            gload16(src + (long)row * ldsrc + sc * 8,
                    (const char*)lds + (r * 256 + wid * 64) * 16);
        }
    };

    stage64(sK, kSrc, 512);
    stage64(sQV[0], qvB, E_);
    stage64(sV[0], vTb, SP_);
    __syncthreads();

    bf16x8 ka[2];
#pragma unroll
    for (int ks = 0; ks < 2; ++ks) {
        const int row = wid * 16 + ll;
        ka[ks] = *reinterpret_cast<const bf16x8*>(
            &sK[row * 64 + (((ks * 4 + lh) ^ (row & 7)) << 3)]);
    }

    float m[4], l[4];
#pragma unroll
    for (int ii = 0; ii < 4; ++ii) { m[ii] = -1e30f; l[ii] = 0.f; }
    f32x4 oacc[4] = {};

    for (int jt = 0; jt < 5; ++jt) {
        const int j0 = jt * 64;
        const int cur = jt & 1;
        if (jt < 4) {                       // prefetch next tiles (other buffer)
            stage64(sQV[cur ^ 1], qvB + (long)(j0 + 64) * E_, E_);
            stage64(sV[cur ^ 1], vTb + j0 + 64, SP_);
        }
        f32x4 s[4] = {};
        __builtin_amdgcn_s_setprio(1);
#pragma unroll
        for (int ks = 0; ks < 2; ++ks)
#pragma unroll
            for (int nf = 0; nf < 4; ++nf) {
                const int row = nf * 16 + ll;
                const bf16x8 qb = *reinterpret_cast<const bf16x8*>(
                    &sQV[cur][row * 64 + (((ks * 4 + lh) ^ (row & 7)) << 3)]);
                s[nf] = __builtin_amdgcn_mfma_f32_16x16x32_bf16(ka[ks], qb, s[nf], 0, 0, 0);
            }
        __builtin_amdgcn_s_setprio(0);
        float pv[4][4];
#pragma unroll
        for (int ii = 0; ii < 4; ++ii) {
            float mx = -1e30f;
#pragma unroll
            for (int nf = 0; nf < 4; ++nf) {
                float sv = s[nf][ii] * INV_SQRT_E;
                if (j0 + nf * 16 + ll >= S_) sv = -1e30f;   // mask pad cols
                pv[nf][ii] = sv;
                mx = fmaxf(mx, sv);
            }
#pragma unroll
            for (int msk = 1; msk < 16; msk <<= 1) mx = fmaxf(mx, __shfl_xor(mx, msk));
            const float mnew = fmaxf(m[ii], mx);
            const float resc = __expf(m[ii] - mnew);
            m[ii] = mnew;
            float sum = 0.f;
#pragma unroll
            for (int nf = 0; nf < 4; ++nf) {
                const float e = __expf(pv[nf][ii] - mnew);
                pv[nf][ii] = e; sum += e;
            }
#pragma unroll
            for (int msk = 1; msk < 16; msk <<= 1) sum += __shfl_xor(sum, msk);
            l[ii] = l[ii] * resc + sum;
#pragma unroll
            for (int pf = 0; pf < 4; ++pf) oacc[pf][ii] *= resc;
        }
        __bf16* sPw = &sP[wid][0];
#pragma unroll
        for (int nf = 0; nf < 4; ++nf)
#pragma unroll
            for (int ii = 0; ii < 4; ++ii) {
                const int row = lh * 4 + ii, col = ll + 16 * nf;
                sPw[row * 64 + ((((col >> 3) ^ (row & 7)) << 3) | (col & 7))] =
                    (__bf16)pv[nf][ii];
            }
        __builtin_amdgcn_s_setprio(1);
#pragma unroll
        for (int ks = 0; ks < 2; ++ks) {
            const bf16x8 pa = *reinterpret_cast<const bf16x8*>(
                &sPw[ll * 64 + (((ks * 4 + lh) ^ (ll & 7)) << 3)]);
#pragma unroll
            for (int pf = 0; pf < 4; ++pf) {
                const int row = pf * 16 + ll;
                const bf16x8 vb = *reinterpret_cast<const bf16x8*>(
                    &sV[cur][row * 64 + (((ks * 4 + lh) ^ (row & 7)) << 3)]);
                oacc[pf] = __builtin_amdgcn_mfma_f32_16x16x32_bf16(pa, vb, oacc[pf], 0, 0, 0);
            }
        }
        __builtin_amdgcn_s_setprio(0);
        if (jt < 4) __syncthreads();        // drains prefetch; guards buffer swap
    }
#pragma unroll
    for (int ii = 0; ii < 4; ++ii) {
        const int i = i0 + wid * 16 + lh * 4 + ii;
        if (i >= S_) continue;
        const float invl = 1.f / l[ii];
#pragma unroll
        for (int pf = 0; pf < 4; ++pf)
            ocat[((long)(b * S_ + i)) * E_ + h * 64 + pf * 16 + ll] =
                (__bf16)(oacc[pf][ii] * invl);
    }
}

// ---------------- LayerNorm: one wave/row; bf16 x + bf16 partial slabs ------
__global__ void ln_kernel(const __bf16* x,
                          const __bf16* __restrict__ parts, int nparts, long pstride,
                          const float* __restrict__ g, const float* __restrict__ bb,
                          __bf16* outb, int skip_cond, int nrows)
{
    const int row = blockIdx.x * 4 + (threadIdx.x >> 6);
    if (row >= nrows) return;
    const int lane = threadIdx.x & 63;
    const long xrow = skip_cond ? (long)row + (row >> 8) + 1 : (long)row;
    const bf16x8 xa = *reinterpret_cast<const bf16x8*>(x + xrow * E_ + lane * 8);
    float e[8];
#pragma unroll
    for (int i = 0; i < 8; ++i) e[i] = (float)xa[i];
    for (int p = 0; p < nparts; ++p) {
        const bf16x8 pv = *reinterpret_cast<const bf16x8*>(
            parts + (long)p * pstride + (long)row * E_ + lane * 8);
#pragma unroll
        for (int i = 0; i < 8; ++i) e[i] += (float)pv[i];
    }
    float s = 0.f;
#pragma unroll
    for (int i = 0; i < 8; ++i) s += e[i];
#pragma unroll
    for (int o = 32; o; o >>= 1) s += __shfl_xor(s, o);
    const float mean = s * (1.f / 512.f);
    float v = 0.f;
#pragma unroll
    for (int i = 0; i < 8; ++i) { e[i] -= mean; v += e[i] * e[i]; }
#pragma unroll
    for (int o = 32; o; o >>= 1) v += __shfl_xor(v, o);
    const float inv = rsqrtf(v * (1.f / 512.f) + 1e-5f);
    const float4* gp = (const float4*)g + lane * 2;
    const float4* bp = (const float4*)bb + lane * 2;
    const float4 g0 = gp[0], g1 = gp[1], bb0 = bp[0], bb1 = bp[1];
    const float gv[8] = {g0.x, g0.y, g0.z, g0.w, g1.x, g1.y, g1.z, g1.w};
    const float bv[8] = {bb0.x, bb0.y, bb0.z, bb0.w, bb1.x, bb1.y, bb1.z, bb1.w};
    bf16x8 ov;
#pragma unroll
    for (int i = 0; i < 8; ++i) ov[i] = (__bf16)(e[i] * inv * gv[i] + bv[i]);
    *reinterpret_cast<bf16x8*>(outb + (long)row * E_ + lane * 8) = ov;
}

// ---------------- converts / data movement ----------------
__global__ void conv_straight(const float* __restrict__ in, __bf16* __restrict__ out, long n)
{
    const long i = (long)blockIdx.x * 256 + threadIdx.x;
    if (i < n) out[i] = (__bf16)in[i];
}

// LDS-tiled transpose: out[c*R + r] = in[r*C + c]  (fp32 -> bf16), once
__global__ void conv_transpose(const float* __restrict__ in, __bf16* __restrict__ out,
                               int R, int C)
{
    __shared__ float tile[32][33];
    const int r0 = blockIdx.x * 32, c0 = blockIdx.y * 32;
    const int tx = threadIdx.x & 31, ty = threadIdx.x >> 5;
#pragma unroll
    for (int i = 0; i < 32; i += 8) {
        const int rr = r0 + ty + i, cc = c0 + tx;
        tile[ty + i][tx] = (rr < R && cc < C) ? in[(long)rr * C + cc] : 0.f;
    }
    __syncthreads();
#pragma unroll
    for (int i = 0; i < 32; i += 8) {
        const int cc = c0 + ty + i, rr = r0 + tx;
        if (cc < C && rr < R) out[(long)cc * R + rr] = (__bf16)tile[tx][ty + i];
    }
}

// ALL layers' weight transposes; FLAT grid (4224 real blocks, no dead blocks).
// [256r x 32c] tile, LDS [256][33] col-swizzled; 512B-run coalesced writes.
// Per layer 352 tiles: j0 0-31, j1 32-63, j2 64-95, j3 96-223, j4 224-351.
__global__ void wconv_all(const float* __restrict__ enc_kp, const float* __restrict__ dec_kp,
                          const float* __restrict__ enc_vp, const float* __restrict__ dec_vp,
                          const float* __restrict__ enc_lift, const float* __restrict__ dec_lift,
                          const float* __restrict__ enc_w1, const float* __restrict__ dec_w1,
                          const float* __restrict__ enc_w2, const float* __restrict__ dec_w2,
                          __bf16* __restrict__ kvT, __bf16* __restrict__ liftT,
                          __bf16* __restrict__ w1T, __bf16* __restrict__ w2T)
{
    const int id  = blockIdx.x;              // 0..4223
    const int lyr = id / 352;
    int t = id % 352;
    int j;
    if      (t < 32)  { j = 0; }
    else if (t < 64)  { j = 1; t -= 32; }
    else if (t < 96)  { j = 2; t -= 64; }
    else if (t < 224) { j = 3; t -= 96; }
    else              { j = 4; t -= 224; }

    const bool enc = lyr < 6;
    const int li = enc ? lyr : lyr - 6;
    const float* src; __bf16* dst; int R, C;
    switch (j) {
        case 0:  src = (enc ? enc_kp : dec_kp) + (long)li * 262144;
                 dst = kvT + (long)lyr * 524288;            R = 512; C = 64;   break;
        case 1:  src = (enc ? enc_vp : dec_vp) + (long)li * 262144;
                 dst = kvT + (long)lyr * 524288 + 262144;   R = 512; C = 64;   break;
        case 2:  src = (enc ? enc_lift : dec_lift) + (long)li * 262144;
                 dst = liftT + (long)lyr * 262144;          R = 512; C = 512;  break;
        case 3:  src = (enc ? enc_w1 : dec_w1) + (long)li * 1048576;
                 dst = w1T + (long)lyr * 1048576;           R = 512; C = 2048; break;
        default: src = (enc ? enc_w2 : dec_w2) + (long)li * 1048576;
                 dst = w2T + (long)lyr * 1048576;           R = 2048; C = 512; break;
    }
    const int tC = C >> 5;           // 32-col blocks
    const int tRc = R >> 8;          // 256-row chunks
    const int cb = t % tC;  t /= tC;
    const int rch = t % tRc; t /= tRc;
    const int bt = t;                // batch (j0/j1 heads)
    const long bs = (long)R * C;
    const float* ip = src + (long)bt * bs + (long)rch * 256 * C + cb * 32;
    __bf16* op = dst + (long)bt * bs + (long)cb * 32 * R + rch * 256;

    __shared__ float tile[256][33];
#pragma unroll
    for (int p = 0; p < 8; ++p) {
        const int t2 = threadIdx.x + p * 256;
        const int r = t2 >> 3, c4 = (t2 & 7) * 4;
        const float4 v4 = *reinterpret_cast<const float4*>(&ip[(long)r * C + c4]);
        const int sw = (r >> 3) & 31;
        tile[r][(c4)     ^ sw] = v4.x;
        tile[r][(c4 + 1) ^ sw] = v4.y;
        tile[r][(c4 + 2) ^ sw] = v4.z;
        tile[r][(c4 + 3) ^ sw] = v4.w;
    }
    __syncthreads();
#pragma unroll
    for (int p = 0; p < 4; ++p) {
        const int id2 = threadIdx.x + p * 256;
        const int c = id2 >> 5, rc = id2 & 31;
        bf16x8 v;
#pragma unroll
        for (int k = 0; k < 8; ++k)
            v[k] = (__bf16)tile[rc * 8 + k][c ^ rc];
        *reinterpret_cast<bf16x8*>(&op[(long)c * R + rc * 8]) = v;
    }
}

// qh for ALL 12 layers -> (12,8,288,288) bf16 zero-padded; one wave per row.
__global__ void conv_qh_all(const float* __restrict__ enc_qh,
                            const float* __restrict__ dec_qh,
                            __bf16* __restrict__ out)
{
    const int rowid = blockIdx.x * 4 + (threadIdx.x >> 6);   // < 96*288 = 27648
    const int lane = threadIdx.x & 63;
    if (lane >= 36) return;
    const int s = rowid % 288;
    const int slab = rowid / 288;            // lyr*8 + h
    const int h = slab & 7, lyr = slab >> 3;
    __bf16* op = out + (long)slab * SLAB + (long)s * SP_;
    const float* src = (lyr < 6 ? enc_qh + (long)lyr * 8 * S_ * S_
                                : dec_qh + (long)(lyr - 6) * 8 * S_ * S_)
                       + ((long)h * S_ + s) * S_;
    const int t0 = lane * 8;
    bf16x8 v;
#pragma unroll
    for (int k = 0; k < 8; ++k) {
        const int t = t0 + k;
        v[k] = (__bf16)((s < S_ && t < S_) ? src[t] : 0.f);
    }
    *reinterpret_cast<bf16x8*>(op + t0) = v;
}

// zero vT pad columns t=257..287 (once; epilogue never touches them)
__global__ void vpad_kernel(__bf16* __restrict__ vT)
{
    const int i = blockIdx.x * 256 + threadIdx.x;
    if (i >= 128 * 64 * 31) return;
    const int t = 257 + (i % 31);
    const long rp = i / 31;
    vT[rp * SP_ + t] = (__bf16)0.f;
}

// im2col -> bf16
__global__ void im2col_kernel(const float* __restrict__ x, __bf16* __restrict__ xcol)
{
    const int idx = blockIdx.x * 256 + threadIdx.x;
    if (idx >= MTOK * 192) return;
    const int m = idx / 192, k = idx % 192;
    const int b = m >> 8, t = m & 255;
    const int ph = t >> 4, pw = t & 15;
    const int c = k >> 6, rr = k & 63;
    const int p = rr >> 3, q = rr & 7;
    xcol[idx] = (__bf16)x[(((long)(b * C_ + c) * HIMG) + ph * 8 + p) * HIMG + pw * 8 + q];
}

// cond MLP (two layers) + pos -> zb row 0 of each batch
__global__ void cond_kernel(const float* __restrict__ y,
                            const float* __restrict__ w1, const float* __restrict__ b1,
                            const float* __restrict__ w2, const float* __restrict__ b2,
                            const float* __restrict__ pos, __bf16* __restrict__ zb)
{
    __shared__ float c1[512];
    const int b = blockIdx.x;
    const int e = threadIdx.x;   // 512
    float v = y[b * 3 + 0] * w1[e] + y[b * 3 + 1] * w1[512 + e]
            + y[b * 3 + 2] * w1[1024 + e] + b1[e];
    v = v > 0.f ? v : 0.2f * v;
    c1[e] = v;
    __syncthreads();
    float acc = b2[e];
    for (int k = 0; k < 512; ++k) acc += c1[k] * w2[k * 512 + e];
    acc = acc > 0.f ? acc : 0.2f * acc;
    zb[(long)b * S_ * E_ + e] = (__bf16)(acc + pos[e]);
}

// zb[b,1+t,e] = tok[(b*256+t)*512+e] + pos[(1+t)*512+e]
__global__ void assemble_kernel(const __bf16* __restrict__ tok,
                                const float* __restrict__ pos,
                                __bf16* __restrict__ zb)
{
    const int idx = blockIdx.x * 256 + threadIdx.x;
    if (idx >= MTOK * E_) return;
    const int m = idx >> 9;
    const int e = idx & 511;
    const int b = m >> 8, t = m & 255;
    const float o = (float)tok[idx] + pos[(1 + t) * E_ + e];
    zb[((long)b * S_ + 1 + t) * E_ + e] = (__bf16)o;
}

// scatter deconv tmp -> (B,C,H,W) + bias
__global__ void scatter_kernel(const float* __restrict__ dtmp,
                               const float* __restrict__ db,
                               float* __restrict__ out)
{
    const int idx = blockIdx.x * 256 + threadIdx.x;
    if (idx >= B_ * C_ * HIMG * HIMG) return;
    const int b  = idx / (C_ * HIMG * HIMG);
    const int rm = idx % (C_ * HIMG * HIMG);
    const int c  = rm / (HIMG * HIMG);
    const int hh = (rm % (HIMG * HIMG)) / HIMG;
    const int ww = rm % HIMG;
    const int ph = hh >> 3, p = hh & 7;
    const int pw = ww >> 3, q = ww & 7;
    out[idx] = dtmp[((long)(b * 256 + ph * 16 + pw)) * 192 + c * 64 + p * 8 + q] + db[c];
}

// ---------------- host launch ----------------
extern "C" void kernel_launch(void* const* d_in, const int* in_sizes, int n_in,
                              void* d_out, int out_size, void* d_ws, size_t ws_size,
                              hipStream_t stream)
{
    const float* x        = (const float*)d_in[0];
    const float* y        = (const float*)d_in[1];
    const float* patch_w  = (const float*)d_in[2];
    const float* patch_b  = (const float*)d_in[3];
    const float* cond_w1  = (const float*)d_in[4];
    const float* cond_b1  = (const float*)d_in[5];
    const float* cond_w2  = (const float*)d_in[6];
    const float* cond_b2  = (const float*)d_in[7];
    const float* pos      = (const float*)d_in[8];
    const float* enc_vp   = (const float*)d_in[9];
    const float* enc_kp   = (const float*)d_in[10];
    const float* enc_qh   = (const float*)d_in[11];
    const float* enc_lift = (const float*)d_in[12];
    const float* enc_ln1g = (const float*)d_in[13];
    const float* enc_ln1b = (const float*)d_in[14];
    const float* enc_w1   = (const float*)d_in[15];
    const float* enc_b1   = (const float*)d_in[16];
    const float* enc_w2   = (const float*)d_in[17];
    const float* enc_b2   = (const float*)d_in[18];
    const float* enc_ln2g = (const float*)d_in[19];
    const float* enc_ln2b = (const float*)d_in[20];
    const float* dec_vp   = (const float*)d_in[21];
    const float* dec_kp   = (const float*)d_in[22];
    const float* dec_qh   = (const float*)d_in[23];
    const float* dec_lift = (const float*)d_in[24];
    const float* dec_ln2g = (const float*)d_in[25];
    const float* dec_ln2b = (const float*)d_in[26];
    const float* dec_w1   = (const float*)d_in[27];
    const float* dec_b1   = (const float*)d_in[28];
    const float* dec_w2   = (const float*)d_in[29];
    const float* dec_b2   = (const float*)d_in[30];
    const float* dec_ln3g = (const float*)d_in[31];
    const float* dec_ln3b = (const float*)d_in[32];
    const float* final_g  = (const float*)d_in[33];
    const float* final_b  = (const float*)d_in[34];
    const float* deconv_w = (const float*)d_in[35];
    const float* deconv_b = (const float*)d_in[36];
    float* out = (float*)d_out;

    // ---- workspace carve-up (64B-aligned); ws = 256 MiB ----
    char* wp = (char*)d_ws;
    auto alloc_f32 = [&](long n) { float* p = (float*)wp; wp += ((n * 4 + 63) & ~63LL); return p; };
    auto alloc_bf  = [&](long n) { __bf16* p = (__bf16*)wp; wp += ((n * 2 + 63) & ~63LL); return p; };

    float*  dtmp   = alloc_f32(786432);
    __bf16* zb     = alloc_bf(4352L * 512);         // residual state (bf16)
    __bf16* tok    = alloc_bf(4096L * 512);
    __bf16* xcolb  = alloc_bf(786432);
    __bf16* kcat   = alloc_bf(4352L * 512);         // K projection
    __bf16* qvcat  = alloc_bf(4352L * 512);
    __bf16* ocat   = alloc_bf(4352L * 512);
    __bf16* vT     = alloc_bf(128L * 64 * SP_);
    __bf16* psl    = alloc_bf(4L * PS);             // split-K partial slabs
    __bf16* hidden = alloc_bf(4224L * 2048);
    __bf16* gbuf   = alloc_bf(4096L * 512);
    __bf16* pwb    = alloc_bf(512L * 192);
    __bf16* dwTb   = alloc_bf(192L * 512);
    __bf16* kvT12  = alloc_bf(12L * 524288);        // per-layer [kpT;vpT]
    __bf16* liftT12= alloc_bf(12L * 262144);
    __bf16* w1T12  = alloc_bf(12L * 1048576);
    __bf16* w2T12  = alloc_bf(12L * 1048576);
    __bf16* qhb12  = alloc_bf(12L * 8 * SLAB + 96L * SP_);
    (void)ws_size; (void)in_sizes; (void)n_in; (void)out_size;

    const dim3 blk(256);

    // ---- one-time converts (all layers) ----
    conv_straight<<<dim3(384), blk, 0, stream>>>(patch_w, pwb, 98304);
    conv_transpose<<<dim3(16, 6), blk, 0, stream>>>(deconv_w, dwTb, 512, 192);
    wconv_all<<<dim3(4224), blk, 0, stream>>>(
        enc_kp, dec_kp, enc_vp, dec_vp, enc_lift, dec_lift,
        enc_w1, dec_w1, enc_w2, dec_w2, kvT12, liftT12, w1T12, w2T12);
    conv_qh_all<<<dim3(6912), blk, 0, stream>>>(enc_qh, dec_qh, qhb12);
    vpad_kernel<<<dim3(992), blk, 0, stream>>>(vT);

    // ---- patch embedding + cond + assemble ----
    im2col_kernel<<<dim3(3072), blk, 0, stream>>>(x, xcolb);
    gemm_k<2, 2, false, false, false><<<dim3(256), blk, 0, stream>>>(
        xcolb, 192, pwb, 192, tok, 512, patch_b, 1.f, MTOK, 512, 192, 8, nullptr);
    cond_kernel<<<dim3(B_), dim3(512), 0, stream>>>(y, cond_w1, cond_b1,
                                                    cond_w2, cond_b2, pos, zb);
    assemble_kernel<<<dim3(8192), blk, 0, stream>>>(tok, pos, zb);

    for (int l = 0; l < 12; ++l) {
        const bool enc = l < 6;
        const int  li  = enc ? l : l - 6;
        const float* g1   = (enc ? enc_ln1g : dec_ln2g) + li * E_;
        const float* bb1  = (enc ? enc_ln1b : dec_ln2b) + li * E_;
        const float* fb1  = (enc ? enc_b1   : dec_b1)   + li * HID_;
        const float* fb2  = (enc ? enc_b2   : dec_b2)   + li * E_;
        const float* g2   = (enc ? enc_ln2g : dec_ln3g) + li * E_;
        const float* bb2  = (enc ? enc_ln2b : dec_ln3b) + li * E_;
        const __bf16* kvTb   = kvT12 + (long)l * 524288;
        const __bf16* liftTb = liftT12 + (long)l * 262144;
        const __bf16* w1Tb   = w1T12 + (long)l * 1048576;
        const __bf16* w2Tb   = w2T12 + (long)l * 1048576;
        const __bf16* qhb    = qhb12 + (long)l * 8 * SLAB;

        // attention: KV proj (V written transposed into vT) -> qv -> fused attn
        gemm_k<2, 2, false, false, true><<<dim3(528), blk, 0, stream>>>(
            zb, 512, kvTb, 512, kcat, 512, nullptr, 1.f, MSEQ, 1024, 512, 16, vT);
        qv_k<<<dim3(3, 1, 128), blk, 0, stream>>>(qhb, vT, qvcat);
        fa_k<<<dim3(5, 128), blk, 0, stream>>>(kcat, qvcat, vT, ocat);
        // lift: non-split (K=512, 16 K-steps) -> single bf16 slab, LN sums 1 part
        gemm_k<2, 2, false, false, false><<<dim3(264), blk, 0, stream>>>(
            ocat, 512, liftTb, 512, psl, 512, nullptr, 1.f, MSEQ, 512, 512, 8, nullptr);
        ln_kernel<<<dim3(1028), blk, 0, stream>>>(zb, psl, 1, PS, g1, bb1,
                                                  zb, 0, MSEQ);

        // FFN (FFN1 1056 blocks; FFN2 split-K x2, Kp=1024)
        gemm_k<2, 2, true, false, false><<<dim3(1056), blk, 0, stream>>>(
            zb, 512, w1Tb, 512, hidden, 2048, fb1, 1.f, MSEQ, HID_, 512, 32, nullptr);
        gemm_split_k<2, 2><<<dim3(264, 2), blk, 0, stream>>>(
            hidden, 2048, w2Tb, 2048, psl, PS, fb2, MSEQ, 512, HID_, 2, 8);
        ln_kernel<<<dim3(1028), blk, 0, stream>>>(zb, psl, 2, PS, g2, bb2,
                                                  zb, 0, MSEQ);
    }

    // final LN (drop cond token) -> bf16 grid
    ln_kernel<<<dim3(1024), blk, 0, stream>>>(zb, nullptr, 0, 0, final_g, final_b,
                                              gbuf, 1, MTOK);
    // deconv GEMM + scatter
    gemm_k<2, 2, false, true, false><<<dim3(96), blk, 0, stream>>>(
        gbuf, 512, dwTb, 512, dtmp, 192, nullptr, 1.f, MTOK, 192, 512, 3, nullptr);
    scatter_kernel<<<dim3(3072), blk, 0, stream>>>(dtmp, deconv_b, out);
}

// Round 16
// 1490.874 us; speedup vs baseline: 1.0208x; 1.0208x over previous
//
#include <hip/hip_runtime.h>
#include <stdint.h>
#include <math.h>

// ---------------- problem constants ----------------
#define B_    16
#define C_    3
#define HIMG  128
#define E_    512
#define NH_   8
#define S_    257
#define T_    256
#define MTOK  4096         // B*T
#define MSEQ  4112         // B*S
#define HID_  2048
#define SP_   288          // S padded to mult of 32
#define SLAB  (288*288)
#define PS    2105344L     // partial-slab stride (MSEQ*512 elements)
#define INV_SQRT_E 0.044194173824159216f

typedef __attribute__((ext_vector_type(8))) __bf16 bf16x8;
typedef __attribute__((ext_vector_type(4))) float f32x4;

// ---------------- global->LDS direct (16B/lane) ----------------
__device__ __forceinline__ void gload16(const void* g, const void* lds)
{
    __builtin_amdgcn_global_load_lds(
        (const __attribute__((address_space(1))) uint32_t*)(uintptr_t)g,
        (__attribute__((address_space(3))) uint32_t*)(uint32_t)(uintptr_t)lds,
        16, 0, 0);
}

// ---------------- bf16 MFMA GEMM core (3-slot ring, depth-2) ----------------
// C[M,N] = scale * (A[M,K] . Bt[N,K]^T) (+bias[n]) (leaky opt)
// A, Bt bf16 row-major. BM=WMW*64, BN=WNW*32. Wave tile 64x32 (4x2 frags).
// LDS: [row][chunk^((row>>1)&3)] 16B chunks, pre-swizzled global source.
// Pipeline: 3 LDS slots (37KB -> 4 blocks/CU), prefetch depth 2, counted
// vmcnt + raw s_barrier; s_setprio(1) around the MFMA cluster (T5).
// VSPLIT: cols n>=512 are V-projection -> written transposed into vTout[bh][p][t].
// Staged rows beyond M must be readable (callers pad allocations); K % 32 == 0.
template<int WMW, int WNW, bool LEAKY, bool OUTF32, bool VSPLIT>
__device__ __forceinline__ void gemm_core(
    const __bf16* __restrict__ A, int lda,
    const __bf16* __restrict__ Bt, int ldb,
    void* __restrict__ C, int ldc,
    const float* __restrict__ bias, float scale,
    int M, int N, int K, int tm, int tn, __bf16* __restrict__ vTout)
{
    constexpr int BM  = WMW * 64;
    constexpr int BN  = WNW * 32;
    constexpr int T   = WMW * WNW * 64;
    constexpr int ACH = BM * 4;              // 16B chunks per A tile
    constexpr int BCH = BN * 4;
    constexpr int LPT = ACH / T + BCH / T;   // vmem instrs per thread per stage
    __shared__ __align__(16) __bf16 sA[3][BM * 32];
    __shared__ __align__(16) __bf16 sB[3][BN * 32];

    const int tid  = threadIdx.x;
    const int lane = tid & 63;
    const int wid  = tid >> 6;
    const int wm   = wid / WNW;
    const int wn   = wid % WNW;
    const int lh   = lane >> 4;
    const int ll   = lane & 15;

    const __bf16* Ab = A + (long)tm * BM * lda;
    const __bf16* Bb = Bt + (long)tn * BN * ldb;

    f32x4 acc[4][2] = {};
    const int nst = K >> 5;

    auto stage = [&](int buf, int k0) {
#pragma unroll
        for (int rr = 0; rr < ACH / T; ++rr) {
            const int L = rr * T + tid;
            const int row = L >> 2;
            const int gch = (L & 3) ^ ((row >> 1) & 3);
            gload16(Ab + (long)row * lda + k0 + gch * 8,
                    (const char*)(&sA[buf][0]) + (rr * T + (wid << 6)) * 16);
        }
#pragma unroll
        for (int rr = 0; rr < BCH / T; ++rr) {
            const int L = rr * T + tid;
            const int row = L >> 2;
            const int gch = (L & 3) ^ ((row >> 1) & 3);
            gload16(Bb + (long)row * ldb + k0 + gch * 8,
                    (const char*)(&sB[buf][0]) + (rr * T + (wid << 6)) * 16);
        }
    };

    stage(0, 0);
    if (nst > 1) stage(1, 32);

    int cur = 0, pre = 2;
    for (int st = 0; st < nst; ++st) {
        if (st + 1 < nst) asm volatile("s_waitcnt vmcnt(%0)" :: "n"(LPT) : "memory");
        else              asm volatile("s_waitcnt vmcnt(0)" ::: "memory");
        __builtin_amdgcn_s_barrier();
        __builtin_amdgcn_sched_barrier(0);

        if (st + 2 < nst) {
            stage(pre, (st + 2) << 5);
            pre = (pre == 2) ? 0 : pre + 1;
        }

        bf16x8 afr[4], bfr[2];
#pragma unroll
        for (int i = 0; i < 4; ++i) {
            const int rw = wm * 64 + i * 16 + ll;
            const int c  = lh ^ ((rw >> 1) & 3);
            afr[i] = *reinterpret_cast<const bf16x8*>(&sA[cur][rw * 32 + c * 8]);
        }
#pragma unroll
        for (int j = 0; j < 2; ++j) {
            const int rw = wn * 32 + j * 16 + ll;
            const int c  = lh ^ ((rw >> 1) & 3);
            bfr[j] = *reinterpret_cast<const bf16x8*>(&sB[cur][rw * 32 + c * 8]);
        }
        __builtin_amdgcn_s_setprio(1);
#pragma unroll
        for (int i = 0; i < 4; ++i)
#pragma unroll
            for (int j = 0; j < 2; ++j)
                acc[i][j] = __builtin_amdgcn_mfma_f32_16x16x32_bf16(
                                afr[i], bfr[j], acc[i][j], 0, 0, 0);
        __builtin_amdgcn_s_setprio(0);
        cur = (cur == 2) ? 0 : cur + 1;
    }

    // epilogue: D frag col=lane&15, row=(lane>>4)*4+reg  [m89-verified]
#pragma unroll
    for (int i = 0; i < 4; ++i)
#pragma unroll
        for (int ii = 0; ii < 4; ++ii) {
            const int m = tm * BM + wm * 64 + i * 16 + lh * 4 + ii;
            if (m >= M) continue;
#pragma unroll
            for (int j = 0; j < 2; ++j) {
                const int n = tn * BN + wn * 32 + j * 16 + ll;
                if (n >= N) continue;
                float v = acc[i][j][ii] * scale;
                if (bias) v += bias[n];
                if (LEAKY) v = v > 0.f ? v : 0.2f * v;
                if (VSPLIT && n >= 512) {
                    const int b = m / S_;
                    const int t = m - b * S_;
                    const int hp = n - 512;
                    vTout[(((long)(b * 8 + (hp >> 6)) * 64) + (hp & 63)) * SP_ + t] =
                        (__bf16)v;
                } else if (OUTF32) {
                    ((float*)C)[(long)m * ldc + n] = v;
                } else {
                    ((__bf16*)C)[(long)m * ldc + n] = (__bf16)v;
                }
            }
        }
}

__device__ __forceinline__ int xcd_swizzle(int wg, int nwg)
{
    const int q = nwg >> 3, r = nwg & 7;
    if (q == 0) return wg;
    const int xcd = wg & 7, off = wg >> 3;
    return (xcd < r ? xcd * (q + 1) : r * (q + 1) + (xcd - r) * q) + off;
}

// flat-grid GEMM, bijective XCD swizzle, tn fastest (A panels L2-resident)
template<int WMW, int WNW, bool LEAKY, bool OUTF32, bool VSPLIT>
__global__ __launch_bounds__(WMW * WNW * 64, 4) void gemm_k(
    const __bf16* __restrict__ A, int lda, const __bf16* __restrict__ Bt, int ldb,
    void* __restrict__ C, int ldc, const float* __restrict__ bias, float scale,
    int M, int N, int K, int ntn, __bf16* __restrict__ vTout)
{
    const int wg = xcd_swizzle(blockIdx.x, gridDim.x);
    gemm_core<WMW, WNW, LEAKY, OUTF32, VSPLIT>(A, lda, Bt, ldb, C, ldc, bias, scale,
                                               M, N, K, wg / ntn, wg % ntn, vTout);
}

// split-K GEMM: blockIdx.y = K-part; bf16 partial slabs; consumer sums.
template<int WMW, int WNW>
__global__ __launch_bounds__(WMW * WNW * 64, 4) void gemm_split_k(
    const __bf16* __restrict__ A, int lda, const __bf16* __restrict__ Bt, int ldb,
    __bf16* __restrict__ P, long pstride, const float* __restrict__ bias,
    int M, int N, int K, int npart, int ntn)
{
    const int part = blockIdx.y;
    const int Kp = K / npart;
    const int wg = xcd_swizzle(blockIdx.x, gridDim.x);
    gemm_core<WMW, WNW, false, false, false>(A + (long)part * Kp, lda,
                                             Bt + (long)part * Kp, ldb,
                                             P + (long)part * pstride, N,
                                             part == 0 ? bias : nullptr, 1.f,
                                             M, N, Kp, wg / ntn, wg % ntn, nullptr);
}

// qv: qv[b,s,(h,p)] = sum_t qh[h,s,t] * v[b,t,(h,p)]  (4-wave core)
__global__ __launch_bounds__(256, 4) void qv_k(const __bf16* __restrict__ qhb,
                                               const __bf16* __restrict__ vT,
                                               __bf16* __restrict__ qvcat)
{
    const int bh = blockIdx.z, b = bh >> 3, h = bh & 7;
    gemm_core<2, 2, false, false, false>(qhb + (long)h * SLAB, SP_,
                                         vT + (long)bh * 64 * SP_, SP_,
                                         qvcat + (long)b * S_ * E_ + h * 64, E_,
                                         nullptr, 1.f, S_, 64, SP_, blockIdx.x, 0,
                                         nullptr);
}

// ---------------- fused attention: scores -> online softmax -> PV -----------
// grid (5 i-tiles, 128 bh), 256 threads (4 waves, 16 i-rows each).
// QV/V double-buffered: prefetch jt+1 during compute; one barrier per tile.
__global__ __launch_bounds__(256) void fa_k(const __bf16* __restrict__ kcat,
                                            const __bf16* __restrict__ qvcat,
                                            const __bf16* __restrict__ vT,
                                            __bf16* __restrict__ ocat)
{
    __shared__ __align__(16) __bf16 sK[64 * 64], sQV[2][64 * 64], sV[2][64 * 64];
    __shared__ __align__(16) __bf16 sP[4][16 * 64];
    const int bh = blockIdx.y, b = bh >> 3, h = bh & 7;
    const int i0 = blockIdx.x * 64;
    const int tid = threadIdx.x, lane = tid & 63, wid = tid >> 6;
    const int ll = lane & 15, lh = lane >> 4;

    const __bf16* kSrc = kcat + ((long)(b * S_ + i0)) * 512 + h * 64;
    const __bf16* qvB  = qvcat + (long)b * S_ * E_ + h * 64;
    const __bf16* vTb  = vT + (long)bh * 64 * SP_;

    auto stage64 = [&](__bf16* lds, const __bf16* src, int ldsrc) {
#pragma unroll
        for (int r = 0; r < 2; ++r) {
            const int L = r * 256 + wid * 64 + lane;
            const int row = L >> 3, c = L & 7;
            const int sc = c ^ (row & 7);
            gload16(src + (long)row * ldsrc + sc * 8,
                    (const char*)lds + (r * 256 + wid * 64) * 16);
        }
    };

    stage64(sK, kSrc, 512);
    stage64(sQV[0], qvB, E_);
    stage64(sV[0], vTb, SP_);
    __syncthreads();

    bf16x8 ka[2];
#pragma unroll
    for (int ks = 0; ks < 2; ++ks) {
        const int row = wid * 16 + ll;
        ka[ks] = *reinterpret_cast<const bf16x8*>(
            &sK[row * 64 + (((ks * 4 + lh) ^ (row & 7)) << 3)]);
    }

    float m[4], l[4];
#pragma unroll
    for (int ii = 0; ii < 4; ++ii) { m[ii] = -1e30f; l[ii] = 0.f; }
    f32x4 oacc[4] = {};

    for (int jt = 0; jt < 5; ++jt) {
        const int j0 = jt * 64;
        const int cur = jt & 1;
        if (jt < 4) {                       // prefetch next tiles (other buffer)
            stage64(sQV[cur ^ 1], qvB + (long)(j0 + 64) * E_, E_);
            stage64(sV[cur ^ 1], vTb + j0 + 64, SP_);
        }
        f32x4 s[4] = {};
        __builtin_amdgcn_s_setprio(1);
#pragma unroll
        for (int ks = 0; ks < 2; ++ks)
#pragma unroll
            for (int nf = 0; nf < 4; ++nf) {
                const int row = nf * 16 + ll;
                const bf16x8 qb = *reinterpret_cast<const bf16x8*>(
                    &sQV[cur][row * 64 + (((ks * 4 + lh) ^ (row & 7)) << 3)]);
                s[nf] = __builtin_amdgcn_mfma_f32_16x16x32_bf16(ka[ks], qb, s[nf], 0, 0, 0);
            }
        __builtin_amdgcn_s_setprio(0);
        float pv[4][4];
#pragma unroll
        for (int ii = 0; ii < 4; ++ii) {
            float mx = -1e30f;
#pragma unroll
            for (int nf = 0; nf < 4; ++nf) {
                float sv = s[nf][ii] * INV_SQRT_E;
                if (j0 + nf * 16 + ll >= S_) sv = -1e30f;   // mask pad cols
                pv[nf][ii] = sv;
                mx = fmaxf(mx, sv);
            }
#pragma unroll
            for (int msk = 1; msk < 16; msk <<= 1) mx = fmaxf(mx, __shfl_xor(mx, msk));
            const float mnew = fmaxf(m[ii], mx);
            const float resc = __expf(m[ii] - mnew);
            m[ii] = mnew;
            float sum = 0.f;
#pragma unroll
            for (int nf = 0; nf < 4; ++nf) {
                const float e = __expf(pv[nf][ii] - mnew);
                pv[nf][ii] = e; sum += e;
            }
#pragma unroll
            for (int msk = 1; msk < 16; msk <<= 1) sum += __shfl_xor(sum, msk);
            l[ii] = l[ii] * resc + sum;
#pragma unroll
            for (int pf = 0; pf < 4; ++pf) oacc[pf][ii] *= resc;
        }
        __bf16* sPw = &sP[wid][0];
#pragma unroll
        for (int nf = 0; nf < 4; ++nf)
#pragma unroll
            for (int ii = 0; ii < 4; ++ii) {
                const int row = lh * 4 + ii, col = ll + 16 * nf;
                sPw[row * 64 + ((((col >> 3) ^ (row & 7)) << 3) | (col & 7))] =
                    (__bf16)pv[nf][ii];
            }
        __builtin_amdgcn_s_setprio(1);
#pragma unroll
        for (int ks = 0; ks < 2; ++ks) {
            const bf16x8 pa = *reinterpret_cast<const bf16x8*>(
                &sPw[ll * 64 + (((ks * 4 + lh) ^ (ll & 7)) << 3)]);
#pragma unroll
            for (int pf = 0; pf < 4; ++pf) {
                const int row = pf * 16 + ll;
                const bf16x8 vb = *reinterpret_cast<const bf16x8*>(
                    &sV[cur][row * 64 + (((ks * 4 + lh) ^ (row & 7)) << 3)]);
                oacc[pf] = __builtin_amdgcn_mfma_f32_16x16x32_bf16(pa, vb, oacc[pf], 0, 0, 0);
            }
        }
        __builtin_amdgcn_s_setprio(0);
        if (jt < 4) __syncthreads();        // drains prefetch; guards buffer swap
    }
#pragma unroll
    for (int ii = 0; ii < 4; ++ii) {
        const int i = i0 + wid * 16 + lh * 4 + ii;
        if (i >= S_) continue;
        const float invl = 1.f / l[ii];
#pragma unroll
        for (int pf = 0; pf < 4; ++pf)
            ocat[((long)(b * S_ + i)) * E_ + h * 64 + pf * 16 + ll] =
                (__bf16)(oacc[pf][ii] * invl);
    }
}

// ---------------- LayerNorm: one wave/row; bf16 x + bf16 partial slabs ------
__global__ void ln_kernel(const __bf16* x,
                          const __bf16* __restrict__ parts, int nparts, long pstride,
                          const float* __restrict__ g, const float* __restrict__ bb,
                          __bf16* outb, int skip_cond, int nrows)
{
    const int row = blockIdx.x * 4 + (threadIdx.x >> 6);
    if (row >= nrows) return;
    const int lane = threadIdx.x & 63;
    const long xrow = skip_cond ? (long)row + (row >> 8) + 1 : (long)row;
    const bf16x8 xa = *reinterpret_cast<const bf16x8*>(x + xrow * E_ + lane * 8);
    float e[8];
#pragma unroll
    for (int i = 0; i < 8; ++i) e[i] = (float)xa[i];
    for (int p = 0; p < nparts; ++p) {
        const bf16x8 pv = *reinterpret_cast<const bf16x8*>(
            parts + (long)p * pstride + (long)row * E_ + lane * 8);
#pragma unroll
        for (int i = 0; i < 8; ++i) e[i] += (float)pv[i];
    }
    float s = 0.f;
#pragma unroll
    for (int i = 0; i < 8; ++i) s += e[i];
#pragma unroll
    for (int o = 32; o; o >>= 1) s += __shfl_xor(s, o);
    const float mean = s * (1.f / 512.f);
    float v = 0.f;
#pragma unroll
    for (int i = 0; i < 8; ++i) { e[i] -= mean; v += e[i] * e[i]; }
#pragma unroll
    for (int o = 32; o; o >>= 1) v += __shfl_xor(v, o);
    const float inv = rsqrtf(v * (1.f / 512.f) + 1e-5f);
    const float4* gp = (const float4*)g + lane * 2;
    const float4* bp = (const float4*)bb + lane * 2;
    const float4 g0 = gp[0], g1 = gp[1], bb0 = bp[0], bb1 = bp[1];
    const float gv[8] = {g0.x, g0.y, g0.z, g0.w, g1.x, g1.y, g1.z, g1.w};
    const float bv[8] = {bb0.x, bb0.y, bb0.z, bb0.w, bb1.x, bb1.y, bb1.z, bb1.w};
    bf16x8 ov;
#pragma unroll
    for (int i = 0; i < 8; ++i) ov[i] = (__bf16)(e[i] * inv * gv[i] + bv[i]);
    *reinterpret_cast<bf16x8*>(outb + (long)row * E_ + lane * 8) = ov;
}

// ---------------- converts / data movement ----------------
__global__ void conv_straight(const float* __restrict__ in, __bf16* __restrict__ out, long n)
{
    const long i = (long)blockIdx.x * 256 + threadIdx.x;
    if (i < n) out[i] = (__bf16)in[i];
}

// LDS-tiled transpose: out[c*R + r] = in[r*C + c]  (fp32 -> bf16), once
__global__ void conv_transpose(const float* __restrict__ in, __bf16* __restrict__ out,
                               int R, int C)
{
    __shared__ float tile[32][33];
    const int r0 = blockIdx.x * 32, c0 = blockIdx.y * 32;
    const int tx = threadIdx.x & 31, ty = threadIdx.x >> 5;
#pragma unroll
    for (int i = 0; i < 32; i += 8) {
        const int rr = r0 + ty + i, cc = c0 + tx;
        tile[ty + i][tx] = (rr < R && cc < C) ? in[(long)rr * C + cc] : 0.f;
    }
    __syncthreads();
#pragma unroll
    for (int i = 0; i < 32; i += 8) {
        const int cc = c0 + ty + i, rr = r0 + tx;
        if (cc < C && rr < R) out[(long)cc * R + rr] = (__bf16)tile[tx][ty + i];
    }
}

// ALL layers' weight transposes; FLAT grid (4224 real blocks, no dead blocks).
// [256r x 32c] tile, LDS [256][33] col-swizzled; 512B-run coalesced writes.
// Per layer 352 tiles: j0 0-31, j1 32-63, j2 64-95, j3 96-223, j4 224-351.
__global__ void wconv_all(const float* __restrict__ enc_kp, const float* __restrict__ dec_kp,
                          const float* __restrict__ enc_vp, const float* __restrict__ dec_vp,
                          const float* __restrict__ enc_lift, const float* __restrict__ dec_lift,
                          const float* __restrict__ enc_w1, const float* __restrict__ dec_w1,
                          const float* __restrict__ enc_w2, const float* __restrict__ dec_w2,
                          __bf16* __restrict__ kvT, __bf16* __restrict__ liftT,
                          __bf16* __restrict__ w1T, __bf16* __restrict__ w2T)
{
    const int id  = blockIdx.x;              // 0..4223
    const int lyr = id / 352;
    int t = id % 352;
    int j;
    if      (t < 32)  { j = 0; }
    else if (t < 64)  { j = 1; t -= 32; }
    else if (t < 96)  { j = 2; t -= 64; }
    else if (t < 224) { j = 3; t -= 96; }
    else              { j = 4; t -= 224; }

    const bool enc = lyr < 6;
    const int li = enc ? lyr : lyr - 6;
    const float* src; __bf16* dst; int R, C;
    switch (j) {
        case 0:  src = (enc ? enc_kp : dec_kp) + (long)li * 262144;
                 dst = kvT + (long)lyr * 524288;            R = 512; C = 64;   break;
        case 1:  src = (enc ? enc_vp : dec_vp) + (long)li * 262144;
                 dst = kvT + (long)lyr * 524288 + 262144;   R = 512; C = 64;   break;
        case 2:  src = (enc ? enc_lift : dec_lift) + (long)li * 262144;
                 dst = liftT + (long)lyr * 262144;          R = 512; C = 512;  break;
        case 3:  src = (enc ? enc_w1 : dec_w1) + (long)li * 1048576;
                 dst = w1T + (long)lyr * 1048576;           R = 512; C = 2048; break;
        default: src = (enc ? enc_w2 : dec_w2) + (long)li * 1048576;
                 dst = w2T + (long)lyr * 1048576;           R = 2048; C = 512; break;
    }
    const int tC = C >> 5;           // 32-col blocks
    const int tRc = R >> 8;          // 256-row chunks
    const int cb = t % tC;  t /= tC;
    const int rch = t % tRc; t /= tRc;
    const int bt = t;                // batch (j0/j1 heads)
    const long bs = (long)R * C;
    const float* ip = src + (long)bt * bs + (long)rch * 256 * C + cb * 32;
    __bf16* op = dst + (long)bt * bs + (long)cb * 32 * R + rch * 256;

    __shared__ float tile[256][33];
#pragma unroll
    for (int p = 0; p < 8; ++p) {
        const int t2 = threadIdx.x + p * 256;
        const int r = t2 >> 3, c4 = (t2 & 7) * 4;
        const float4 v4 = *reinterpret_cast<const float4*>(&ip[(long)r * C + c4]);
        const int sw = (r >> 3) & 31;
        tile[r][(c4)     ^ sw] = v4.x;
        tile[r][(c4 + 1) ^ sw] = v4.y;
        tile[r][(c4 + 2) ^ sw] = v4.z;
        tile[r][(c4 + 3) ^ sw] = v4.w;
    }
    __syncthreads();
#pragma unroll
    for (int p = 0; p < 4; ++p) {
        const int id2 = threadIdx.x + p * 256;
        const int c = id2 >> 5, rc = id2 & 31;
        bf16x8 v;
#pragma unroll
        for (int k = 0; k < 8; ++k)
            v[k] = (__bf16)tile[rc * 8 + k][c ^ rc];
        *reinterpret_cast<bf16x8*>(&op[(long)c * R + rc * 8]) = v;
    }
}

// qh for ALL 12 layers -> (12,8,288,288) bf16 zero-padded; one wave per row.
__global__ void conv_qh_all(const float* __restrict__ enc_qh,
                            const float* __restrict__ dec_qh,
                            __bf16* __restrict__ out)
{
    const int rowid = blockIdx.x * 4 + (threadIdx.x >> 6);   // < 96*288 = 27648
    const int lane = threadIdx.x & 63;
    if (lane >= 36) return;
    const int s = rowid % 288;
    const int slab = rowid / 288;            // lyr*8 + h
    const int h = slab & 7, lyr = slab >> 3;
    __bf16* op = out + (long)slab * SLAB + (long)s * SP_;
    const float* src = (lyr < 6 ? enc_qh + (long)lyr * 8 * S_ * S_
                                : dec_qh + (long)(lyr - 6) * 8 * S_ * S_)
                       + ((long)h * S_ + s) * S_;
    const int t0 = lane * 8;
    bf16x8 v;
#pragma unroll
    for (int k = 0; k < 8; ++k) {
        const int t = t0 + k;
        v[k] = (__bf16)((s < S_ && t < S_) ? src[t] : 0.f);
    }
    *reinterpret_cast<bf16x8*>(op + t0) = v;
}

// zero vT pad columns t=257..287 (once; epilogue never touches them)
__global__ void vpad_kernel(__bf16* __restrict__ vT)
{
    const int i = blockIdx.x * 256 + threadIdx.x;
    if (i >= 128 * 64 * 31) return;
    const int t = 257 + (i % 31);
    const long rp = i / 31;
    vT[rp * SP_ + t] = (__bf16)0.f;
}

// im2col -> bf16
__global__ void im2col_kernel(const float* __restrict__ x, __bf16* __restrict__ xcol)
{
    const int idx = blockIdx.x * 256 + threadIdx.x;
    if (idx >= MTOK * 192) return;
    const int m = idx / 192, k = idx % 192;
    const int b = m >> 8, t = m & 255;
    const int ph = t >> 4, pw = t & 15;
    const int c = k >> 6, rr = k & 63;
    const int p = rr >> 3, q = rr & 7;
    xcol[idx] = (__bf16)x[(((long)(b * C_ + c) * HIMG) + ph * 8 + p) * HIMG + pw * 8 + q];
}

// cond MLP (two layers) + pos -> zb row 0 of each batch
__global__ void cond_kernel(const float* __restrict__ y,
                            const float* __restrict__ w1, const float* __restrict__ b1,
                            const float* __restrict__ w2, const float* __restrict__ b2,
                            const float* __restrict__ pos, __bf16* __restrict__ zb)
{
    __shared__ float c1[512];
    const int b = blockIdx.x;
    const int e = threadIdx.x;   // 512
    float v = y[b * 3 + 0] * w1[e] + y[b * 3 + 1] * w1[512 + e]
            + y[b * 3 + 2] * w1[1024 + e] + b1[e];
    v = v > 0.f ? v : 0.2f * v;
    c1[e] = v;
    __syncthreads();
    float acc = b2[e];
    for (int k = 0; k < 512; ++k) acc += c1[k] * w2[k * 512 + e];
    acc = acc > 0.f ? acc : 0.2f * acc;
    zb[(long)b * S_ * E_ + e] = (__bf16)(acc + pos[e]);
}

// zb[b,1+t,e] = tok[(b*256+t)*512+e] + pos[(1+t)*512+e]
__global__ void assemble_kernel(const __bf16* __restrict__ tok,
                                const float* __restrict__ pos,
                                __bf16* __restrict__ zb)
{
    const int idx = blockIdx.x * 256 + threadIdx.x;
    if (idx >= MTOK * E_) return;
    const int m = idx >> 9;
    const int e = idx & 511;
    const int b = m >> 8, t = m & 255;
    const float o = (float)tok[idx] + pos[(1 + t) * E_ + e];
    zb[((long)b * S_ + 1 + t) * E_ + e] = (__bf16)o;
}

// scatter deconv tmp -> (B,C,H,W) + bias
__global__ void scatter_kernel(const float* __restrict__ dtmp,
                               const float* __restrict__ db,
                               float* __restrict__ out)
{
    const int idx = blockIdx.x * 256 + threadIdx.x;
    if (idx >= B_ * C_ * HIMG * HIMG) return;
    const int b  = idx / (C_ * HIMG * HIMG);
    const int rm = idx % (C_ * HIMG * HIMG);
    const int c  = rm / (HIMG * HIMG);
    const int hh = (rm % (HIMG * HIMG)) / HIMG;
    const int ww = rm % HIMG;
    const int ph = hh >> 3, p = hh & 7;
    const int pw = ww >> 3, q = ww & 7;
    out[idx] = dtmp[((long)(b * 256 + ph * 16 + pw)) * 192 + c * 64 + p * 8 + q] + db[c];
}

// ---------------- host launch ----------------
extern "C" void kernel_launch(void* const* d_in, const int* in_sizes, int n_in,
                              void* d_out, int out_size, void* d_ws, size_t ws_size,
                              hipStream_t stream)
{
    const float* x        = (const float*)d_in[0];
    const float* y        = (const float*)d_in[1];
    const float* patch_w  = (const float*)d_in[2];
    const float* patch_b  = (const float*)d_in[3];
    const float* cond_w1  = (const float*)d_in[4];
    const float* cond_b1  = (const float*)d_in[5];
    const float* cond_w2  = (const float*)d_in[6];
    const float* cond_b2  = (const float*)d_in[7];
    const float* pos      = (const float*)d_in[8];
    const float* enc_vp   = (const float*)d_in[9];
    const float* enc_kp   = (const float*)d_in[10];
    const float* enc_qh   = (const float*)d_in[11];
    const float* enc_lift = (const float*)d_in[12];
    const float* enc_ln1g = (const float*)d_in[13];
    const float* enc_ln1b = (const float*)d_in[14];
    const float* enc_w1   = (const float*)d_in[15];
    const float* enc_b1   = (const float*)d_in[16];
    const float* enc_w2   = (const float*)d_in[17];
    const float* enc_b2   = (const float*)d_in[18];
    const float* enc_ln2g = (const float*)d_in[19];
    const float* enc_ln2b = (const float*)d_in[20];
    const float* dec_vp   = (const float*)d_in[21];
    const float* dec_kp   = (const float*)d_in[22];
    const float* dec_qh   = (const float*)d_in[23];
    const float* dec_lift = (const float*)d_in[24];
    const float* dec_ln2g = (const float*)d_in[25];
    const float* dec_ln2b = (const float*)d_in[26];
    const float* dec_w1   = (const float*)d_in[27];
    const float* dec_b1   = (const float*)d_in[28];
    const float* dec_w2   = (const float*)d_in[29];
    const float* dec_b2   = (const float*)d_in[30];
    const float* dec_ln3g = (const float*)d_in[31];
    const float* dec_ln3b = (const float*)d_in[32];
    const float* final_g  = (const float*)d_in[33];
    const float* final_b  = (const float*)d_in[34];
    const float* deconv_w = (const float*)d_in[35];
    const float* deconv_b = (const float*)d_in[36];
    float* out = (float*)d_out;

    // ---- workspace carve-up (64B-aligned); ws = 256 MiB ----
    char* wp = (char*)d_ws;
    auto alloc_f32 = [&](long n) { float* p = (float*)wp; wp += ((n * 4 + 63) & ~63LL); return p; };
    auto alloc_bf  = [&](long n) { __bf16* p = (__bf16*)wp; wp += ((n * 2 + 63) & ~63LL); return p; };

    float*  dtmp   = alloc_f32(786432);
    __bf16* zb     = alloc_bf(4352L * 512);         // residual state (bf16)
    __bf16* tok    = alloc_bf(4096L * 512);
    __bf16* xcolb  = alloc_bf(786432);
    __bf16* kcat   = alloc_bf(4352L * 512);         // K projection
    __bf16* qvcat  = alloc_bf(4352L * 512);
    __bf16* ocat   = alloc_bf(4352L * 512);
    __bf16* vT     = alloc_bf(128L * 64 * SP_);
    __bf16* psl    = alloc_bf(4L * PS);             // split-K partial slabs
    __bf16* hidden = alloc_bf(4224L * 2048);
    __bf16* gbuf   = alloc_bf(4096L * 512);
    __bf16* pwb    = alloc_bf(512L * 192);
    __bf16* dwTb   = alloc_bf(192L * 512);
    __bf16* kvT12  = alloc_bf(12L * 524288);        // per-layer [kpT;vpT]
    __bf16* liftT12= alloc_bf(12L * 262144);
    __bf16* w1T12  = alloc_bf(12L * 1048576);
    __bf16* w2T12  = alloc_bf(12L * 1048576);
    __bf16* qhb12  = alloc_bf(12L * 8 * SLAB + 96L * SP_);
    (void)ws_size; (void)in_sizes; (void)n_in; (void)out_size;

    const dim3 blk(256);

    // ---- one-time converts (all layers) ----
    conv_straight<<<dim3(384), blk, 0, stream>>>(patch_w, pwb, 98304);
    conv_transpose<<<dim3(16, 6), blk, 0, stream>>>(deconv_w, dwTb, 512, 192);
    wconv_all<<<dim3(4224), blk, 0, stream>>>(
        enc_kp, dec_kp, enc_vp, dec_vp, enc_lift, dec_lift,
        enc_w1, dec_w1, enc_w2, dec_w2, kvT12, liftT12, w1T12, w2T12);
    conv_qh_all<<<dim3(6912), blk, 0, stream>>>(enc_qh, dec_qh, qhb12);
    vpad_kernel<<<dim3(992), blk, 0, stream>>>(vT);

    // ---- patch embedding + cond + assemble ----
    im2col_kernel<<<dim3(3072), blk, 0, stream>>>(x, xcolb);
    gemm_k<2, 2, false, false, false><<<dim3(256), blk, 0, stream>>>(
        xcolb, 192, pwb, 192, tok, 512, patch_b, 1.f, MTOK, 512, 192, 8, nullptr);
    cond_kernel<<<dim3(B_), dim3(512), 0, stream>>>(y, cond_w1, cond_b1,
                                                    cond_w2, cond_b2, pos, zb);
    assemble_kernel<<<dim3(8192), blk, 0, stream>>>(tok, pos, zb);

    for (int l = 0; l < 12; ++l) {
        const bool enc = l < 6;
        const int  li  = enc ? l : l - 6;
        const float* g1   = (enc ? enc_ln1g : dec_ln2g) + li * E_;
        const float* bb1  = (enc ? enc_ln1b : dec_ln2b) + li * E_;
        const float* fb1  = (enc ? enc_b1   : dec_b1)   + li * HID_;
        const float* fb2  = (enc ? enc_b2   : dec_b2)   + li * E_;
        const float* g2   = (enc ? enc_ln2g : dec_ln3g) + li * E_;
        const float* bb2  = (enc ? enc_ln2b : dec_ln3b) + li * E_;
        const __bf16* kvTb   = kvT12 + (long)l * 524288;
        const __bf16* liftTb = liftT12 + (long)l * 262144;
        const __bf16* w1Tb   = w1T12 + (long)l * 1048576;
        const __bf16* w2Tb   = w2T12 + (long)l * 1048576;
        const __bf16* qhb    = qhb12 + (long)l * 8 * SLAB;

        // attention: KV proj (V written transposed into vT) -> qv -> fused attn
        gemm_k<2, 2, false, false, true><<<dim3(528), blk, 0, stream>>>(
            zb, 512, kvTb, 512, kcat, 512, nullptr, 1.f, MSEQ, 1024, 512, 16, vT);
        qv_k<<<dim3(3, 1, 128), blk, 0, stream>>>(qhb, vT, qvcat);
        fa_k<<<dim3(5, 128), blk, 0, stream>>>(kcat, qvcat, vT, ocat);
        // lift: non-split (K=512, 16 K-steps) -> single bf16 slab, LN sums 1 part
        gemm_k<2, 2, false, false, false><<<dim3(264), blk, 0, stream>>>(
            ocat, 512, liftTb, 512, psl, 512, nullptr, 1.f, MSEQ, 512, 512, 8, nullptr);
        ln_kernel<<<dim3(1028), blk, 0, stream>>>(zb, psl, 1, PS, g1, bb1,
                                                  zb, 0, MSEQ);

        // FFN (FFN1 1056 blocks; FFN2 split-K x2, Kp=1024)
        gemm_k<2, 2, true, false, false><<<dim3(1056), blk, 0, stream>>>(
            zb, 512, w1Tb, 512, hidden, 2048, fb1, 1.f, MSEQ, HID_, 512, 32, nullptr);
        gemm_split_k<2, 2><<<dim3(264, 2), blk, 0, stream>>>(
            hidden, 2048, w2Tb, 2048, psl, PS, fb2, MSEQ, 512, HID_, 2, 8);
        ln_kernel<<<dim3(1028), blk, 0, stream>>>(zb, psl, 2, PS, g2, bb2,
                                                  zb, 0, MSEQ);
    }

    // final LN (drop cond token) -> bf16 grid
    ln_kernel<<<dim3(1024), blk, 0, stream>>>(zb, nullptr, 0, 0, final_g, final_b,
                                              gbuf, 1, MTOK);
    // deconv GEMM + scatter
    gemm_k<2, 2, false, true, false><<<dim3(96), blk, 0, stream>>>(
        gbuf, 512, dwTb, 512, dtmp, 192, nullptr, 1.f, MTOK, 192, 512, 3, nullptr);
    scatter_kernel<<<dim3(3072), blk, 0, stream>>>(dtmp, deconv_b, out);
}

// Round 17
// 1488.800 us; speedup vs baseline: 1.0222x; 1.0014x over previous
//
#include <hip/hip_runtime.h>
#include <stdint.h>
#include <math.h>

// ---------------- problem constants ----------------
#define B_    16
#define C_    3
#define HIMG  128
#define E_    512
#define NH_   8
#define S_    257
#define T_    256
#define MTOK  4096         // B*T
#define MSEQ  4112         // B*S
#define HID_  2048
#define SP_   288          // S padded to mult of 32
#define SLAB  (288*288)
#define PS    2105344L     // partial-slab stride (MSEQ*512 elements)
#define INV_SQRT_E 0.044194173824159216f

typedef __attribute__((ext_vector_type(8))) __bf16 bf16x8;
typedef __attribute__((ext_vector_type(4))) float f32x4;

// ---------------- global->LDS direct (16B/lane) ----------------
__device__ __forceinline__ void gload16(const void* g, const void* lds)
{
    __builtin_amdgcn_global_load_lds(
        (const __attribute__((address_space(1))) uint32_t*)(uintptr_t)g,
        (__attribute__((address_space(3))) uint32_t*)(uint32_t)(uintptr_t)lds,
        16, 0, 0);
}

// ---------------- bf16 MFMA GEMM core (3-slot ring, depth-2) ----------------
// C[M,N] = scale * (A[M,K] . Bt[N,K]^T) (+bias[n]) (leaky opt)
// A, Bt bf16 row-major. BM=WMW*64, BN=WNW*32. Wave tile 64x32 (4x2 frags).
// LDS: [row][chunk^((row>>1)&3)] 16B chunks, pre-swizzled global source.
// Pipeline: 3 LDS slots (37KB -> 4 blocks/CU), prefetch depth 2, counted
// vmcnt + raw s_barrier; s_setprio(1) around the MFMA cluster (T5).
// VSPLIT: cols n>=512 are V-projection -> written transposed into vTout[bh][p][t].
// Staged rows beyond M must be readable (callers pad allocations); K % 32 == 0.
template<int WMW, int WNW, bool LEAKY, bool OUTF32, bool VSPLIT>
__device__ __forceinline__ void gemm_core(
    const __bf16* __restrict__ A, int lda,
    const __bf16* __restrict__ Bt, int ldb,
    void* __restrict__ C, int ldc,
    const float* __restrict__ bias, float scale,
    int M, int N, int K, int tm, int tn, __bf16* __restrict__ vTout)
{
    constexpr int BM  = WMW * 64;
    constexpr int BN  = WNW * 32;
    constexpr int T   = WMW * WNW * 64;
    constexpr int ACH = BM * 4;              // 16B chunks per A tile
    constexpr int BCH = BN * 4;
    constexpr int LPT = ACH / T + BCH / T;   // vmem instrs per thread per stage
    __shared__ __align__(16) __bf16 sA[3][BM * 32];
    __shared__ __align__(16) __bf16 sB[3][BN * 32];

    const int tid  = threadIdx.x;
    const int lane = tid & 63;
    const int wid  = tid >> 6;
    const int wm   = wid / WNW;
    const int wn   = wid % WNW;
    const int lh   = lane >> 4;
    const int ll   = lane & 15;

    const __bf16* Ab = A + (long)tm * BM * lda;
    const __bf16* Bb = Bt + (long)tn * BN * ldb;

    f32x4 acc[4][2] = {};
    const int nst = K >> 5;

    auto stage = [&](int buf, int k0) {
#pragma unroll
        for (int rr = 0; rr < ACH / T; ++rr) {
            const int L = rr * T + tid;
            const int row = L >> 2;
            const int gch = (L & 3) ^ ((row >> 1) & 3);
            gload16(Ab + (long)row * lda + k0 + gch * 8,
                    (const char*)(&sA[buf][0]) + (rr * T + (wid << 6)) * 16);
        }
#pragma unroll
        for (int rr = 0; rr < BCH / T; ++rr) {
            const int L = rr * T + tid;
            const int row = L >> 2;
            const int gch = (L & 3) ^ ((row >> 1) & 3);
            gload16(Bb + (long)row * ldb + k0 + gch * 8,
                    (const char*)(&sB[buf][0]) + (rr * T + (wid << 6)) * 16);
        }
    };

    stage(0, 0);
    if (nst > 1) stage(1, 32);

    int cur = 0, pre = 2;
    for (int st = 0; st < nst; ++st) {
        if (st + 1 < nst) asm volatile("s_waitcnt vmcnt(%0)" :: "n"(LPT) : "memory");
        else              asm volatile("s_waitcnt vmcnt(0)" ::: "memory");
        __builtin_amdgcn_s_barrier();
        __builtin_amdgcn_sched_barrier(0);

        if (st + 2 < nst) {
            stage(pre, (st + 2) << 5);
            pre = (pre == 2) ? 0 : pre + 1;
        }

        bf16x8 afr[4], bfr[2];
#pragma unroll
        for (int i = 0; i < 4; ++i) {
            const int rw = wm * 64 + i * 16 + ll;
            const int c  = lh ^ ((rw >> 1) & 3);
            afr[i] = *reinterpret_cast<const bf16x8*>(&sA[cur][rw * 32 + c * 8]);
        }
#pragma unroll
        for (int j = 0; j < 2; ++j) {
            const int rw = wn * 32 + j * 16 + ll;
            const int c  = lh ^ ((rw >> 1) & 3);
            bfr[j] = *reinterpret_cast<const bf16x8*>(&sB[cur][rw * 32 + c * 8]);
        }
        __builtin_amdgcn_s_setprio(1);
#pragma unroll
        for (int i = 0; i < 4; ++i)
#pragma unroll
            for (int j = 0; j < 2; ++j)
                acc[i][j] = __builtin_amdgcn_mfma_f32_16x16x32_bf16(
                                afr[i], bfr[j], acc[i][j], 0, 0, 0);
        __builtin_amdgcn_s_setprio(0);
        cur = (cur == 2) ? 0 : cur + 1;
    }

    // epilogue: D frag col=lane&15, row=(lane>>4)*4+reg  [m89-verified]
#pragma unroll
    for (int i = 0; i < 4; ++i)
#pragma unroll
        for (int ii = 0; ii < 4; ++ii) {
            const int m = tm * BM + wm * 64 + i * 16 + lh * 4 + ii;
            if (m >= M) continue;
#pragma unroll
            for (int j = 0; j < 2; ++j) {
                const int n = tn * BN + wn * 32 + j * 16 + ll;
                if (n >= N) continue;
                float v = acc[i][j][ii] * scale;
                if (bias) v += bias[n];
                if (LEAKY) v = v > 0.f ? v : 0.2f * v;
                if (VSPLIT && n >= 512) {
                    const int b = m / S_;
                    const int t = m - b * S_;
                    const int hp = n - 512;
                    vTout[(((long)(b * 8 + (hp >> 6)) * 64) + (hp & 63)) * SP_ + t] =
                        (__bf16)v;
                } else if (OUTF32) {
                    ((float*)C)[(long)m * ldc + n] = v;
                } else {
                    ((__bf16*)C)[(long)m * ldc + n] = (__bf16)v;
                }
            }
        }
}

__device__ __forceinline__ int xcd_swizzle(int wg, int nwg)
{
    const int q = nwg >> 3, r = nwg & 7;
    if (q == 0) return wg;
    const int xcd = wg & 7, off = wg >> 3;
    return (xcd < r ? xcd * (q + 1) : r * (q + 1) + (xcd - r) * q) + off;
}

// flat-grid GEMM, bijective XCD swizzle, tn fastest (A panels L2-resident)
template<int WMW, int WNW, bool LEAKY, bool OUTF32, bool VSPLIT>
__global__ __launch_bounds__(WMW * WNW * 64, 4) void gemm_k(
    const __bf16* __restrict__ A, int lda, const __bf16* __restrict__ Bt, int ldb,
    void* __restrict__ C, int ldc, const float* __restrict__ bias, float scale,
    int M, int N, int K, int ntn, __bf16* __restrict__ vTout)
{
    const int wg = xcd_swizzle(blockIdx.x, gridDim.x);
    gemm_core<WMW, WNW, LEAKY, OUTF32, VSPLIT>(A, lda, Bt, ldb, C, ldc, bias, scale,
                                               M, N, K, wg / ntn, wg % ntn, vTout);
}

// split-K GEMM: blockIdx.y = K-part; bf16 partial slabs; consumer sums.
template<int WMW, int WNW>
__global__ __launch_bounds__(WMW * WNW * 64, 4) void gemm_split_k(
    const __bf16* __restrict__ A, int lda, const __bf16* __restrict__ Bt, int ldb,
    __bf16* __restrict__ P, long pstride, const float* __restrict__ bias,
    int M, int N, int K, int npart, int ntn)
{
    const int part = blockIdx.y;
    const int Kp = K / npart;
    const int wg = xcd_swizzle(blockIdx.x, gridDim.x);
    gemm_core<WMW, WNW, false, false, false>(A + (long)part * Kp, lda,
                                             Bt + (long)part * Kp, ldb,
                                             P + (long)part * pstride, N,
                                             part == 0 ? bias : nullptr, 1.f,
                                             M, N, Kp, wg / ntn, wg % ntn, nullptr);
}

// qv: qv[b,s,(h,p)] = sum_t qh[h,s,t] * v[b,t,(h,p)]  (4-wave core)
__global__ __launch_bounds__(256, 4) void qv_k(const __bf16* __restrict__ qhb,
                                               const __bf16* __restrict__ vT,
                                               __bf16* __restrict__ qvcat)
{
    const int bh = blockIdx.z, b = bh >> 3, h = bh & 7;
    gemm_core<2, 2, false, false, false>(qhb + (long)h * SLAB, SP_,
                                         vT + (long)bh * 64 * SP_, SP_,
                                         qvcat + (long)b * S_ * E_ + h * 64, E_,
                                         nullptr, 1.f, S_, 64, SP_, blockIdx.x, 0,
                                         nullptr);
}

// ---------------- fused attention: scores -> online softmax -> PV -----------
// grid (5 i-tiles, 128 bh), 256 threads (4 waves, 16 i-rows each).
// QV/V double-buffered: prefetch jt+1 during compute; one barrier per tile.
__global__ __launch_bounds__(256) void fa_k(const __bf16* __restrict__ kcat,
                                            const __bf16* __restrict__ qvcat,
                                            const __bf16* __restrict__ vT,
                                            __bf16* __restrict__ ocat)
{
    __shared__ __align__(16) __bf16 sK[64 * 64], sQV[2][64 * 64], sV[2][64 * 64];
    __shared__ __align__(16) __bf16 sP[4][16 * 64];
    const int bh = blockIdx.y, b = bh >> 3, h = bh & 7;
    const int i0 = blockIdx.x * 64;
    const int tid = threadIdx.x, lane = tid & 63, wid = tid >> 6;
    const int ll = lane & 15, lh = lane >> 4;

    const __bf16* kSrc = kcat + ((long)(b * S_ + i0)) * 512 + h * 64;
    const __bf16* qvB  = qvcat + (long)b * S_ * E_ + h * 64;
    const __bf16* vTb  = vT + (long)bh * 64 * SP_;

    auto stage64 = [&](__bf16* lds, const __bf16* src, int ldsrc) {
#pragma unroll
        for (int r = 0; r < 2; ++r) {
            const int L = r * 256 + wid * 64 + lane;
            const int row = L >> 3, c = L & 7;
            const int sc = c ^ (row & 7);
            gload16(src + (long)row * ldsrc + sc * 8,
                    (const char*)lds + (r * 256 + wid * 64) * 16);
        }
    };

    stage64(sK, kSrc, 512);
    stage64(sQV[0], qvB, E_);
    stage64(sV[0], vTb, SP_);
    __syncthreads();

    bf16x8 ka[2];
#pragma unroll
    for (int ks = 0; ks < 2; ++ks) {
        const int row = wid * 16 + ll;
        ka[ks] = *reinterpret_cast<const bf16x8*>(
            &sK[row * 64 + (((ks * 4 + lh) ^ (row & 7)) << 3)]);
    }

    float m[4], l[4];
#pragma unroll
    for (int ii = 0; ii < 4; ++ii) { m[ii] = -1e30f; l[ii] = 0.f; }
    f32x4 oacc[4] = {};

    for (int jt = 0; jt < 5; ++jt) {
        const int j0 = jt * 64;
        const int cur = jt & 1;
        if (jt < 4) {                       // prefetch next tiles (other buffer)
            stage64(sQV[cur ^ 1], qvB + (long)(j0 + 64) * E_, E_);
            stage64(sV[cur ^ 1], vTb + j0 + 64, SP_);
        }
        f32x4 s[4] = {};
        __builtin_amdgcn_s_setprio(1);
#pragma unroll
        for (int ks = 0; ks < 2; ++ks)
#pragma unroll
            for (int nf = 0; nf < 4; ++nf) {
                const int row = nf * 16 + ll;
                const bf16x8 qb = *reinterpret_cast<const bf16x8*>(
                    &sQV[cur][row * 64 + (((ks * 4 + lh) ^ (row & 7)) << 3)]);
                s[nf] = __builtin_amdgcn_mfma_f32_16x16x32_bf16(ka[ks], qb, s[nf], 0, 0, 0);
            }
        __builtin_amdgcn_s_setprio(0);
        float pv[4][4];
#pragma unroll
        for (int ii = 0; ii < 4; ++ii) {
            float mx = -1e30f;
#pragma unroll
            for (int nf = 0; nf < 4; ++nf) {
                float sv = s[nf][ii] * INV_SQRT_E;
                if (j0 + nf * 16 + ll >= S_) sv = -1e30f;   // mask pad cols
                pv[nf][ii] = sv;
                mx = fmaxf(mx, sv);
            }
#pragma unroll
            for (int msk = 1; msk < 16; msk <<= 1) mx = fmaxf(mx, __shfl_xor(mx, msk));
            const float mnew = fmaxf(m[ii], mx);
            const float resc = __expf(m[ii] - mnew);
            m[ii] = mnew;
            float sum = 0.f;
#pragma unroll
            for (int nf = 0; nf < 4; ++nf) {
                const float e = __expf(pv[nf][ii] - mnew);
                pv[nf][ii] = e; sum += e;
            }
#pragma unroll
            for (int msk = 1; msk < 16; msk <<= 1) sum += __shfl_xor(sum, msk);
            l[ii] = l[ii] * resc + sum;
#pragma unroll
            for (int pf = 0; pf < 4; ++pf) oacc[pf][ii] *= resc;
        }
        __bf16* sPw = &sP[wid][0];
#pragma unroll
        for (int nf = 0; nf < 4; ++nf)
#pragma unroll
            for (int ii = 0; ii < 4; ++ii) {
                const int row = lh * 4 + ii, col = ll + 16 * nf;
                sPw[row * 64 + ((((col >> 3) ^ (row & 7)) << 3) | (col & 7))] =
                    (__bf16)pv[nf][ii];
            }
        __builtin_amdgcn_s_setprio(1);
#pragma unroll
        for (int ks = 0; ks < 2; ++ks) {
            const bf16x8 pa = *reinterpret_cast<const bf16x8*>(
                &sPw[ll * 64 + (((ks * 4 + lh) ^ (ll & 7)) << 3)]);
#pragma unroll
            for (int pf = 0; pf < 4; ++pf) {
                const int row = pf * 16 + ll;
                const bf16x8 vb = *reinterpret_cast<const bf16x8*>(
                    &sV[cur][row * 64 + (((ks * 4 + lh) ^ (row & 7)) << 3)]);
                oacc[pf] = __builtin_amdgcn_mfma_f32_16x16x32_bf16(pa, vb, oacc[pf], 0, 0, 0);
            }
        }
        __builtin_amdgcn_s_setprio(0);
        if (jt < 4) __syncthreads();        // drains prefetch; guards buffer swap
    }
#pragma unroll
    for (int ii = 0; ii < 4; ++ii) {
        const int i = i0 + wid * 16 + lh * 4 + ii;
        if (i >= S_) continue;
        const float invl = 1.f / l[ii];
#pragma unroll
        for (int pf = 0; pf < 4; ++pf)
            ocat[((long)(b * S_ + i)) * E_ + h * 64 + pf * 16 + ll] =
                (__bf16)(oacc[pf][ii] * invl);
    }
}

// ---------------- LayerNorm: one wave/row; bf16 x + bf16 partial slabs ------
__global__ void ln_kernel(const __bf16* x,
                          const __bf16* __restrict__ parts, int nparts, long pstride,
                          const float* __restrict__ g, const float* __restrict__ bb,
                          __bf16* outb, int skip_cond, int nrows)
{
    const int row = blockIdx.x * 4 + (threadIdx.x >> 6);
    if (row >= nrows) return;
    const int lane = threadIdx.x & 63;
    const long xrow = skip_cond ? (long)row + (row >> 8) + 1 : (long)row;
    const bf16x8 xa = *reinterpret_cast<const bf16x8*>(x + xrow * E_ + lane * 8);
    float e[8];
#pragma unroll
    for (int i = 0; i < 8; ++i) e[i] = (float)xa[i];
    for (int p = 0; p < nparts; ++p) {
        const bf16x8 pv = *reinterpret_cast<const bf16x8*>(
            parts + (long)p * pstride + (long)row * E_ + lane * 8);
#pragma unroll
        for (int i = 0; i < 8; ++i) e[i] += (float)pv[i];
    }
    float s = 0.f;
#pragma unroll
    for (int i = 0; i < 8; ++i) s += e[i];
#pragma unroll
    for (int o = 32; o; o >>= 1) s += __shfl_xor(s, o);
    const float mean = s * (1.f / 512.f);
    float v = 0.f;
#pragma unroll
    for (int i = 0; i < 8; ++i) { e[i] -= mean; v += e[i] * e[i]; }
#pragma unroll
    for (int o = 32; o; o >>= 1) v += __shfl_xor(v, o);
    const float inv = rsqrtf(v * (1.f / 512.f) + 1e-5f);
    const float4* gp = (const float4*)g + lane * 2;
    const float4* bp = (const float4*)bb + lane * 2;
    const float4 g0 = gp[0], g1 = gp[1], bb0 = bp[0], bb1 = bp[1];
    const float gv[8] = {g0.x, g0.y, g0.z, g0.w, g1.x, g1.y, g1.z, g1.w};
    const float bv[8] = {bb0.x, bb0.y, bb0.z, bb0.w, bb1.x, bb1.y, bb1.z, bb1.w};
    bf16x8 ov;
#pragma unroll
    for (int i = 0; i < 8; ++i) ov[i] = (__bf16)(e[i] * inv * gv[i] + bv[i]);
    *reinterpret_cast<bf16x8*>(outb + (long)row * E_ + lane * 8) = ov;
}

// ---------------- fused prologue: all one-time converts in ONE launch -------
// block ranges: [0,4224) wconv | [4224,11136) qh | [11136,14208) im2col |
// [14208,14592) patch_w copy | [14592,14688) deconv transpose | [14688,15680) vpad
#define WC_N 4224
#define QH_N 6912
#define IM_N 3072
#define PW_N 384
#define DT_N 96
#define VP_N 992
__global__ __launch_bounds__(256) void prep_k(
    const float* __restrict__ enc_kp, const float* __restrict__ dec_kp,
    const float* __restrict__ enc_vp, const float* __restrict__ dec_vp,
    const float* __restrict__ enc_lift, const float* __restrict__ dec_lift,
    const float* __restrict__ enc_w1, const float* __restrict__ dec_w1,
    const float* __restrict__ enc_w2, const float* __restrict__ dec_w2,
    const float* __restrict__ enc_qh, const float* __restrict__ dec_qh,
    const float* __restrict__ x, const float* __restrict__ patch_w,
    const float* __restrict__ deconv_w,
    __bf16* __restrict__ kvT, __bf16* __restrict__ liftT,
    __bf16* __restrict__ w1T, __bf16* __restrict__ w2T,
    __bf16* __restrict__ qhb, __bf16* __restrict__ xcol,
    __bf16* __restrict__ pwb, __bf16* __restrict__ dwT,
    __bf16* __restrict__ vT)
{
    __shared__ float tile[256][33];
    int id = blockIdx.x;

    if (id < WC_N) {
        // ---- weight transposes: [256r x 32c] tiles, 512B-run writes ----
        const int lyr = id / 352;
        int t = id % 352;
        int j;
        if      (t < 32)  { j = 0; }
        else if (t < 64)  { j = 1; t -= 32; }
        else if (t < 96)  { j = 2; t -= 64; }
        else if (t < 224) { j = 3; t -= 96; }
        else              { j = 4; t -= 224; }
        const bool enc = lyr < 6;
        const int li = enc ? lyr : lyr - 6;
        const float* src; __bf16* dst; int R, C;
        switch (j) {
            case 0:  src = (enc ? enc_kp : dec_kp) + (long)li * 262144;
                     dst = kvT + (long)lyr * 524288;            R = 512; C = 64;   break;
            case 1:  src = (enc ? enc_vp : dec_vp) + (long)li * 262144;
                     dst = kvT + (long)lyr * 524288 + 262144;   R = 512; C = 64;   break;
            case 2:  src = (enc ? enc_lift : dec_lift) + (long)li * 262144;
                     dst = liftT + (long)lyr * 262144;          R = 512; C = 512;  break;
            case 3:  src = (enc ? enc_w1 : dec_w1) + (long)li * 1048576;
                     dst = w1T + (long)lyr * 1048576;           R = 512; C = 2048; break;
            default: src = (enc ? enc_w2 : dec_w2) + (long)li * 1048576;
                     dst = w2T + (long)lyr * 1048576;           R = 2048; C = 512; break;
        }
        const int tC = C >> 5;
        const int tRc = R >> 8;
        const int cb = t % tC;  t /= tC;
        const int rch = t % tRc; t /= tRc;
        const int bt = t;
        const long bs = (long)R * C;
        const float* ip = src + (long)bt * bs + (long)rch * 256 * C + cb * 32;
        __bf16* op = dst + (long)bt * bs + (long)cb * 32 * R + rch * 256;
#pragma unroll
        for (int p = 0; p < 8; ++p) {
            const int t2 = threadIdx.x + p * 256;
            const int r = t2 >> 3, c4 = (t2 & 7) * 4;
            const float4 v4 = *reinterpret_cast<const float4*>(&ip[(long)r * C + c4]);
            const int sw = (r >> 3) & 31;
            tile[r][(c4)     ^ sw] = v4.x;
            tile[r][(c4 + 1) ^ sw] = v4.y;
            tile[r][(c4 + 2) ^ sw] = v4.z;
            tile[r][(c4 + 3) ^ sw] = v4.w;
        }
        __syncthreads();
#pragma unroll
        for (int p = 0; p < 4; ++p) {
            const int id2 = threadIdx.x + p * 256;
            const int c = id2 >> 5, rc = id2 & 31;
            bf16x8 v;
#pragma unroll
            for (int k = 0; k < 8; ++k)
                v[k] = (__bf16)tile[rc * 8 + k][c ^ rc];
            *reinterpret_cast<bf16x8*>(&op[(long)c * R + rc * 8]) = v;
        }
        return;
    }
    id -= WC_N;

    if (id < QH_N) {
        // ---- qh fp32 -> (12,8,288,288) bf16 zero-padded; one wave per row ----
        const int rowid = id * 4 + (threadIdx.x >> 6);
        const int lane = threadIdx.x & 63;
        if (lane >= 36) return;
        const int s = rowid % 288;
        const int slab = rowid / 288;
        const int h = slab & 7, lyr = slab >> 3;
        __bf16* op = qhb + (long)slab * SLAB + (long)s * SP_;
        const float* src = (lyr < 6 ? enc_qh + (long)lyr * 8 * S_ * S_
                                    : dec_qh + (long)(lyr - 6) * 8 * S_ * S_)
                           + ((long)h * S_ + s) * S_;
        const int t0 = lane * 8;
        bf16x8 v;
#pragma unroll
        for (int k = 0; k < 8; ++k) {
            const int t = t0 + k;
            v[k] = (__bf16)((s < S_ && t < S_) ? src[t] : 0.f);
        }
        *reinterpret_cast<bf16x8*>(op + t0) = v;
        return;
    }
    id -= QH_N;

    if (id < IM_N) {
        // ---- im2col -> bf16 ----
        const int idx = id * 256 + threadIdx.x;
        const int m = idx / 192, k = idx % 192;
        const int b = m >> 8, t = m & 255;
        const int ph = t >> 4, pw = t & 15;
        const int c = k >> 6, rr = k & 63;
        const int p = rr >> 3, q = rr & 7;
        xcol[idx] = (__bf16)x[(((long)(b * C_ + c) * HIMG) + ph * 8 + p) * HIMG + pw * 8 + q];
        return;
    }
    id -= IM_N;

    if (id < PW_N) {
        // ---- patch_w fp32 -> bf16 straight copy (98304 elems) ----
        const int i = id * 256 + threadIdx.x;
        pwb[i] = (__bf16)patch_w[i];
        return;
    }
    id -= PW_N;

    if (id < DT_N) {
        // ---- deconv_w (512x192) transpose -> dwT (192,512) bf16 ----
        const int rt = id & 15, ct = id >> 4;     // 16 x 6
        const int r0 = rt * 32, c0 = ct * 32;
        const int tx = threadIdx.x & 31, ty = threadIdx.x >> 5;
        float (*t32)[33] = (float(*)[33])tile;
#pragma unroll
        for (int i = 0; i < 32; i += 8)
            t32[ty + i][tx] = deconv_w[(long)(r0 + ty + i) * 192 + c0 + tx];
        __syncthreads();
#pragma unroll
        for (int i = 0; i < 32; i += 8)
            dwT[(long)(c0 + ty + i) * 512 + r0 + tx] = (__bf16)t32[tx][ty + i];
        return;
    }
    id -= DT_N;

    // ---- zero vT pad columns t=257..287 ----
    const int i = id * 256 + threadIdx.x;
    if (i >= 128 * 64 * 31) return;
    const int t = 257 + (i % 31);
    const long rp = i / 31;
    vT[rp * SP_ + t] = (__bf16)0.f;
}

// cond MLP (two layers) + pos -> zb row 0 of each batch
__global__ void cond_kernel(const float* __restrict__ y,
                            const float* __restrict__ w1, const float* __restrict__ b1,
                            const float* __restrict__ w2, const float* __restrict__ b2,
                            const float* __restrict__ pos, __bf16* __restrict__ zb)
{
    __shared__ float c1[512];
    const int b = blockIdx.x;
    const int e = threadIdx.x;   // 512
    float v = y[b * 3 + 0] * w1[e] + y[b * 3 + 1] * w1[512 + e]
            + y[b * 3 + 2] * w1[1024 + e] + b1[e];
    v = v > 0.f ? v : 0.2f * v;
    c1[e] = v;
    __syncthreads();
    float acc = b2[e];
    for (int k = 0; k < 512; ++k) acc += c1[k] * w2[k * 512 + e];
    acc = acc > 0.f ? acc : 0.2f * acc;
    zb[(long)b * S_ * E_ + e] = (__bf16)(acc + pos[e]);
}

// zb[b,1+t,e] = tok[(b*256+t)*512+e] + pos[(1+t)*512+e]
__global__ void assemble_kernel(const __bf16* __restrict__ tok,
                                const float* __restrict__ pos,
                                __bf16* __restrict__ zb)
{
    const int idx = blockIdx.x * 256 + threadIdx.x;
    if (idx >= MTOK * E_) return;
    const int m = idx >> 9;
    const int e = idx & 511;
    const int b = m >> 8, t = m & 255;
    const float o = (float)tok[idx] + pos[(1 + t) * E_ + e];
    zb[((long)b * S_ + 1 + t) * E_ + e] = (__bf16)o;
}

// scatter deconv tmp -> (B,C,H,W) + bias
__global__ void scatter_kernel(const float* __restrict__ dtmp,
                               const float* __restrict__ db,
                               float* __restrict__ out)
{
    const int idx = blockIdx.x * 256 + threadIdx.x;
    if (idx >= B_ * C_ * HIMG * HIMG) return;
    const int b  = idx / (C_ * HIMG * HIMG);
    const int rm = idx % (C_ * HIMG * HIMG);
    const int c  = rm / (HIMG * HIMG);
    const int hh = (rm % (HIMG * HIMG)) / HIMG;
    const int ww = rm % HIMG;
    const int ph = hh >> 3, p = hh & 7;
    const int pw = ww >> 3, q = ww & 7;
    out[idx] = dtmp[((long)(b * 256 + ph * 16 + pw)) * 192 + c * 64 + p * 8 + q] + db[c];
}

// ---------------- host launch ----------------
extern "C" void kernel_launch(void* const* d_in, const int* in_sizes, int n_in,
                              void* d_out, int out_size, void* d_ws, size_t ws_size,
                              hipStream_t stream)
{
    const float* x        = (const float*)d_in[0];
    const float* y        = (const float*)d_in[1];
    const float* patch_w  = (const float*)d_in[2];
    const float* patch_b  = (const float*)d_in[3];
    const float* cond_w1  = (const float*)d_in[4];
    const float* cond_b1  = (const float*)d_in[5];
    const float* cond_w2  = (const float*)d_in[6];
    const float* cond_b2  = (const float*)d_in[7];
    const float* pos      = (const float*)d_in[8];
    const float* enc_vp   = (const float*)d_in[9];
    const float* enc_kp   = (const float*)d_in[10];
    const float* enc_qh   = (const float*)d_in[11];
    const float* enc_lift = (const float*)d_in[12];
    const float* enc_ln1g = (const float*)d_in[13];
    const float* enc_ln1b = (const float*)d_in[14];
    const float* enc_w1   = (const float*)d_in[15];
    const float* enc_b1   = (const float*)d_in[16];
    const float* enc_w2   = (const float*)d_in[17];
    const float* enc_b2   = (const float*)d_in[18];
    const float* enc_ln2g = (const float*)d_in[19];
    const float* enc_ln2b = (const float*)d_in[20];
    const float* dec_vp   = (const float*)d_in[21];
    const float* dec_kp   = (const float*)d_in[22];
    const float* dec_qh   = (const float*)d_in[23];
    const float* dec_lift = (const float*)d_in[24];
    const float* dec_ln2g = (const float*)d_in[25];
    const float* dec_ln2b = (const float*)d_in[26];
    const float* dec_w1   = (const float*)d_in[27];
    const float* dec_b1   = (const float*)d_in[28];
    const float* dec_w2   = (const float*)d_in[29];
    const float* dec_b2   = (const float*)d_in[30];
    const float* dec_ln3g = (const float*)d_in[31];
    const float* dec_ln3b = (const float*)d_in[32];
    const float* final_g  = (const float*)d_in[33];
    const float* final_b  = (const float*)d_in[34];
    const float* deconv_w = (const float*)d_in[35];
    const float* deconv_b = (const float*)d_in[36];
    float* out = (float*)d_out;

    // ---- workspace carve-up (64B-aligned); ws = 256 MiB ----
    char* wp = (char*)d_ws;
    auto alloc_f32 = [&](long n) { float* p = (float*)wp; wp += ((n * 4 + 63) & ~63LL); return p; };
    auto alloc_bf  = [&](long n) { __bf16* p = (__bf16*)wp; wp += ((n * 2 + 63) & ~63LL); return p; };

    float*  dtmp   = alloc_f32(786432);
    __bf16* zb     = alloc_bf(4352L * 512);         // residual state (bf16)
    __bf16* tok    = alloc_bf(4096L * 512);
    __bf16* xcolb  = alloc_bf(786432);
    __bf16* kcat   = alloc_bf(4352L * 512);         // K projection
    __bf16* qvcat  = alloc_bf(4352L * 512);
    __bf16* ocat   = alloc_bf(4352L * 512);
    __bf16* vT     = alloc_bf(128L * 64 * SP_);
    __bf16* psl    = alloc_bf(4L * PS);             // split-K partial slabs
    __bf16* hidden = alloc_bf(4224L * 2048);
    __bf16* gbuf   = alloc_bf(4096L * 512);
    __bf16* pwb    = alloc_bf(512L * 192);
    __bf16* dwTb   = alloc_bf(192L * 512);
    __bf16* kvT12  = alloc_bf(12L * 524288);        // per-layer [kpT;vpT]
    __bf16* liftT12= alloc_bf(12L * 262144);
    __bf16* w1T12  = alloc_bf(12L * 1048576);
    __bf16* w2T12  = alloc_bf(12L * 1048576);
    __bf16* qhb12  = alloc_bf(12L * 8 * SLAB + 96L * SP_);
    (void)ws_size; (void)in_sizes; (void)n_in; (void)out_size;

    const dim3 blk(256);

    // ---- fused one-time prologue (weights, qh, im2col, vpad) ----
    prep_k<<<dim3(WC_N + QH_N + IM_N + PW_N + DT_N + VP_N), blk, 0, stream>>>(
        enc_kp, dec_kp, enc_vp, dec_vp, enc_lift, dec_lift,
        enc_w1, dec_w1, enc_w2, dec_w2, enc_qh, dec_qh,
        x, patch_w, deconv_w,
        kvT12, liftT12, w1T12, w2T12, qhb12, xcolb, pwb, dwTb, vT);

    // ---- patch embedding + cond + assemble ----
    gemm_k<2, 2, false, false, false><<<dim3(256), blk, 0, stream>>>(
        xcolb, 192, pwb, 192, tok, 512, patch_b, 1.f, MTOK, 512, 192, 8, nullptr);
    cond_kernel<<<dim3(B_), dim3(512), 0, stream>>>(y, cond_w1, cond_b1,
                                                    cond_w2, cond_b2, pos, zb);
    assemble_kernel<<<dim3(8192), blk, 0, stream>>>(tok, pos, zb);

    for (int l = 0; l < 12; ++l) {
        const bool enc = l < 6;
        const int  li  = enc ? l : l - 6;
        const float* g1   = (enc ? enc_ln1g : dec_ln2g) + li * E_;
        const float* bb1  = (enc ? enc_ln1b : dec_ln2b) + li * E_;
        const float* fb1  = (enc ? enc_b1   : dec_b1)   + li * HID_;
        const float* fb2  = (enc ? enc_b2   : dec_b2)   + li * E_;
        const float* g2   = (enc ? enc_ln2g : dec_ln3g) + li * E_;
        const float* bb2  = (enc ? enc_ln2b : dec_ln3b) + li * E_;
        const __bf16* kvTb   = kvT12 + (long)l * 524288;
        const __bf16* liftTb = liftT12 + (long)l * 262144;
        const __bf16* w1Tb   = w1T12 + (long)l * 1048576;
        const __bf16* w2Tb   = w2T12 + (long)l * 1048576;
        const __bf16* qhb    = qhb12 + (long)l * 8 * SLAB;

        // attention: KV proj (V written transposed into vT) -> qv -> fused attn
        gemm_k<2, 2, false, false, true><<<dim3(528), blk, 0, stream>>>(
            zb, 512, kvTb, 512, kcat, 512, nullptr, 1.f, MSEQ, 1024, 512, 16, vT);
        qv_k<<<dim3(3, 1, 128), blk, 0, stream>>>(qhb, vT, qvcat);
        fa_k<<<dim3(5, 128), blk, 0, stream>>>(kcat, qvcat, vT, ocat);
        // lift: split-K x2 into bf16 partial slabs (528 blocks), LN sums
        gemm_split_k<2, 2><<<dim3(264, 2), blk, 0, stream>>>(
            ocat, 512, liftTb, 512, psl, PS, nullptr, MSEQ, 512, 512, 2, 8);
        ln_kernel<<<dim3(1028), blk, 0, stream>>>(zb, psl, 2, PS, g1, bb1,
                                                  zb, 0, MSEQ);

        // FFN (FFN1 1056 blocks; FFN2 split-K x2, Kp=1024)
        gemm_k<2, 2, true, false, false><<<dim3(1056), blk, 0, stream>>>(
            zb, 512, w1Tb, 512, hidden, 2048, fb1, 1.f, MSEQ, HID_, 512, 32, nullptr);
        gemm_split_k<2, 2><<<dim3(264, 2), blk, 0, stream>>>(
            hidden, 2048, w2Tb, 2048, psl, PS, fb2, MSEQ, 512, HID_, 2, 8);
        ln_kernel<<<dim3(1028), blk, 0, stream>>>(zb, psl, 2, PS, g2, bb2,
                                                  zb, 0, MSEQ);
    }

    // final LN (drop cond token) -> bf16 grid
    ln_kernel<<<dim3(1024), blk, 0, stream>>>(zb, nullptr, 0, 0, final_g, final_b,
                                              gbuf, 1, MTOK);
    // deconv GEMM + scatter
    gemm_k<2, 2, false, true, false><<<dim3(96), blk, 0, stream>>>(
        gbuf, 512, dwTb, 512, dtmp, 192, nullptr, 1.f, MTOK, 192, 512, 3, nullptr);
    scatter_kernel<<<dim3(3072), blk, 0, stream>>>(dtmp, deconv_b, out);
}